// Round 2
// baseline (50338.330 us; speedup 1.0000x reference)
//
#include <hip/hip_runtime.h>
#include <math.h>

#define Bz 16
#define Sz 900
#define Vz 16
#define Dz 256
#define DCz 128
#define Hz 4
#define Nz 6300
#define TSz 5400
#define DSLOTz 145
#define NSLOTz 48
#define CHROWS 160
#define NCH 40

typedef unsigned short u16;
typedef unsigned int u32;

static __device__ __forceinline__ float sigm(float x){ return 1.0f/(1.0f+__expf(-x)); }
static __device__ __forceinline__ void fma4(float4& a, float s, float4 b){ a.x+=s*b.x; a.y+=s*b.y; a.z+=s*b.z; a.w+=s*b.w; }
static __device__ __forceinline__ float dot4(float4 a, float4 b){ return a.x*b.x + a.y*b.y + a.z*b.z + a.w*b.w; }
static __device__ __forceinline__ float4 f4z(){ float4 z; z.x=0.f; z.y=0.f; z.z=0.f; z.w=0.f; return z; }
static __device__ __forceinline__ float elu1(float x){ return x>0.f ? x+1.f : __expf(x); }

__global__ void k_sentinel(float* out, int nelem){
  int i = blockIdx.x*256 + threadIdx.x;
  if (i < nelem) out[i] = 12345.0f;
}

__global__ void k_zero(float* p, int n){
  int i = blockIdx.x*256 + threadIdx.x;
  if (i < n) p[i] = 0.f;
}

__global__ void k_rope(float* cost, float* sint){
  int i = blockIdx.x*256 + threadIdx.x;
  if (i >= Nz*32) return;
  int n = i>>5, f = i&31;
  double invd = pow(10000.0, -(double)f/32.0);
  double fr = (double)n * invd;
  cost[i] = (float)cos(fr);
  sint[i] = (float)sin(fr);
}

__global__ void k_embed(const int* __restrict__ di, const int* __restrict__ dq,
                        const int* __restrict__ ti, const float* __restrict__ temb,
                        const float* __restrict__ semb, float* __restrict__ h){
  int i = blockIdx.x*256 + threadIdx.x;   // over B*N*64 float4s
  if (i >= Bz*Nz*64) return;
  int dv = i & 63; int bn = i >> 6; int n = bn % Nz; int b = bn / Nz;
  int tok;
  if (n < TSz){
    int nd = n/1800; int r = n - nd*1800;
    // reference: stack([in,out],axis=2).reshape -> [in 0..899 | out 0..899] per demo
    tok = (r < Sz) ? di[(b*3+nd)*Sz + r] : dq[(b*3+nd)*Sz + (r-Sz)];
  } else {
    tok = ti[b*Sz + (n-TSz)];
  }
  const float4* e4 = (const float4*)(temb + (size_t)tok*Dz);
  const float4* s4 = (const float4*)semb;
  float4 v = e4[dv]; float4 s = s4[dv];
  v.x += s.x; v.y += s.y; v.z += s.z; v.w += s.w;
  ((float4*)h)[(size_t)bn*64 + dv] = v;
}

__global__ void k_cache_init(const float* __restrict__ slot_emb, const float* __restrict__ lid,
                             float* __restrict__ cache){
  int i = blockIdx.x*256 + threadIdx.x;
  if (i >= Bz*NSLOTz*DSLOTz) return;
  int c = i % DSLOTz; int sc = (i / DSLOTz) % NSLOTz; int l = sc >> 4;
  float v = 0.f;
  if (c < DCz) v = slot_emb[sc*DCz + c];
  else if (c >= 129 && c < 137) v = lid[l*8 + (c-129)];
  cache[i] = v;
}

__global__ __launch_bounds__(384) void k_proj_cache(const float* __restrict__ cache,
    const float* __restrict__ Wk, const float* __restrict__ Wv,
    float* __restrict__ kread, float* __restrict__ vread){
  __shared__ float crow[DSLOTz];
  int b = blockIdx.x / NSLOTz, sc = blockIdx.x % NSLOTz;
  int t = threadIdx.x;
  const float* cp = cache + (size_t)(b*NSLOTz+sc)*DSLOTz;
  if (t < DSLOTz) crow[t] = cp[t];
  __syncthreads();
  if (t < DCz){
    float a = 0.f;
    for (int r2=0;r2<DSLOTz;r2++) a += crow[r2]*Wk[r2*DCz + t];
    kread[(size_t)(b*NSLOTz+sc)*DCz + t] = a;
  } else {
    int d = t - DCz;
    float a = 0.f;
    for (int r2=0;r2<DSLOTz;r2++) a += crow[r2]*Wv[r2*Dz + d];
    vread[(size_t)(b*NSLOTz+sc)*Dz + d] = a;
  }
}

__global__ __launch_bounds__(256) void k_read_attn(
    const float* __restrict__ kread, const float* __restrict__ vread,
    const float* __restrict__ Wq, const float* __restrict__ Wg, const float* __restrict__ bg,
    float* __restrict__ h){
  __shared__ float sm[12560];        // phase1/2: hrow[16*257] | qL[16*132] | kL[48*132]; phase3: vL[48*256]
  __shared__ float attn_s[16*48];
  __shared__ float gate_s[16];
  float* hrow = sm;
  float* qL   = sm + 4112;
  float* kL   = sm + 6224;
  int t = threadIdx.x;
  int b = blockIdx.y, row0 = blockIdx.x*16;
  float* hb = h + (size_t)b*Nz*Dz;
  for (int i=t;i<16*Dz;i+=256){ int r=i>>8, c=i&255; int n=row0+r; hrow[r*257+c] = (n<Nz)? hb[(size_t)n*Dz+c] : 0.f; }
  for (int i=t;i<NSLOTz*DCz;i+=256){ int s=i>>7, d=i&127; kL[s*132+d] = kread[(size_t)(b*NSLOTz+s)*DCz + d]; }
  __syncthreads();
  if (t<16){
    float a=0.f;
    for (int c=0;c<Dz;c++) a += hrow[t*257+c]*Wg[c];
    gate_s[t] = sigm(a + bg[0]);
  }
  int r = t>>4, c0 = t&15;
  {
    float4 a0=f4z(), a1=f4z();
    for (int kk=0;kk<Dz;kk++){
      float hv = hrow[r*257+kk];
      const float4* wr = (const float4*)(Wq + (size_t)kk*DCz);
      fma4(a0, hv, wr[c0]); fma4(a1, hv, wr[c0+16]);
    }
    ((float4*)qL)[r*33 + c0] = a0;
    ((float4*)qL)[r*33 + 16 + c0] = a1;
  }
  __syncthreads();
  {
    int sb = c0*3;
    const float4* q4 = (const float4*)(qL) + r*33;
    for (int ss=0; ss<3; ss++){
      int s = sb+ss;
      const float4* k4 = (const float4*)(kL) + s*33;
      float a = 0.f;
      for (int d4=0; d4<32; d4++) a += dot4(q4[d4], k4[d4]);
      attn_s[r*48+s] = a * 0.088388347648318447f;
    }
  }
  __syncthreads();
  for (int i=t;i<NSLOTz*Dz;i+=256) sm[i] = vread[(size_t)b*NSLOTz*Dz + i];
  if (t<16){
    float mx = -1e30f;
    for (int s=0;s<48;s++) mx = fmaxf(mx, attn_s[t*48+s]);
    float su = 0.f;
    for (int s=0;s<48;s++){ float e = __expf(attn_s[t*48+s]-mx); attn_s[t*48+s]=e; su+=e; }
    float inv = 1.f/su;
    for (int s=0;s<48;s++) attn_s[t*48+s] *= inv;
  }
  __syncthreads();
  float4 acc[4]; acc[0]=f4z(); acc[1]=f4z(); acc[2]=f4z(); acc[3]=f4z();
  for (int s=0;s<NSLOTz;s++){
    float a = attn_s[r*48+s];
    const float4* v4 = (const float4*)(sm + s*Dz);
    fma4(acc[0], a, v4[c0]); fma4(acc[1], a, v4[c0+16]); fma4(acc[2], a, v4[c0+32]); fma4(acc[3], a, v4[c0+48]);
  }
  int n = row0+r;
  if (n < Nz){
    float g = gate_s[r];
    float4* hp = (float4*)(hb + (size_t)n*Dz);
    #pragma unroll
    for (int j=0;j<4;j++){
      float4 hv = hp[c0+16*j];
      hv.x += g*acc[j].x; hv.y += g*acc[j].y; hv.z += g*acc[j].z; hv.w += g*acc[j].w;
      hp[c0+16*j] = hv;
    }
  }
}

// k/v projection (Wqkv cols 256..768) + rope/elu on k + fused kv-state accumulation.
// grid: (NCH, Bz), 256 threads. Accumulates into kvbuf[(b*H+h)*4160] via atomics.
__global__ __launch_bounds__(256) void k_kv(const float* __restrict__ h,
    const float* __restrict__ Wl, const float* __restrict__ cost, const float* __restrict__ sint,
    float* __restrict__ kvbuf){
  __shared__ float smem[12480];
  float* hrowL = smem;          // 16 x 260
  float* kfL   = smem + 4160;   // 16 x 260
  float* vhL   = smem + 8320;   // 16 x 260
  int t = threadIdx.x;
  int ch = blockIdx.x, b = blockIdx.y;
  int nbase = ch*CHROWS;
  int nend = nbase + CHROWS; if (nend > Nz) nend = Nz;
  const float* hb = h + (size_t)b*Nz*Dz;
  int r = t>>4, c0 = t&15;
  int g = t>>6, d = t&63;
  float acc[64];
  #pragma unroll
  for (int e=0;e<64;e++) acc[e] = 0.f;
  float ks = 0.f;
  for (int n0 = nbase; n0 < nend; n0 += 16){
    for (int i=t;i<16*Dz;i+=256){ int rr=i>>8, c=i&255; int n=n0+rr; hrowL[rr*260+c] = (n<Nz)? hb[(size_t)n*Dz+c] : 0.f; }
    __syncthreads();
    float4 a[8];
    #pragma unroll
    for (int j=0;j<8;j++) a[j]=f4z();
    const float4* h4 = (const float4*)(hrowL) + r*65;
    for (int kk4=0;kk4<64;kk4++){
      float4 hv = h4[kk4];
      const float4* w0 = (const float4*)(Wl + (size_t)(kk4*4+0)*768 + 256);
      const float4* w1 = (const float4*)(Wl + (size_t)(kk4*4+1)*768 + 256);
      const float4* w2 = (const float4*)(Wl + (size_t)(kk4*4+2)*768 + 256);
      const float4* w3 = (const float4*)(Wl + (size_t)(kk4*4+3)*768 + 256);
      #pragma unroll
      for (int j=0;j<8;j++){
        fma4(a[j], hv.x, w0[c0+16*j]);
        fma4(a[j], hv.y, w1[c0+16*j]);
        fma4(a[j], hv.z, w2[c0+16*j]);
        fma4(a[j], hv.w, w3[c0+16*j]);
      }
    }
    int n = n0 + r;
    int valid = (n < nend);
    int nc = valid ? n : 0;
    float4* kf4 = (float4*)(kfL) + r*65;
    float4* vh4 = (float4*)(vhL) + r*65;
    #pragma unroll
    for (int j=0;j<4;j++){
      float4 kin = a[j];
      int wb = (c0+16*j)*4;          // col within 256-wide k block
      int fi = (wb&63)>>1;
      float co0 = cost[nc*32+fi],   si0 = sint[nc*32+fi];
      float co1 = cost[nc*32+fi+1], si1 = sint[nc*32+fi+1];
      float r0 = kin.x*co0 - kin.y*si0;
      float r1 = kin.x*si0 + kin.y*co0;
      float r2 = kin.z*co1 - kin.w*si1;
      float r3 = kin.z*si1 + kin.w*co1;
      float4 ko;
      ko.x = valid ? elu1(r0) : 0.f;
      ko.y = valid ? elu1(r1) : 0.f;
      ko.z = valid ? elu1(r2) : 0.f;
      ko.w = valid ? elu1(r3) : 0.f;
      kf4[c0+16*j] = ko;
      vh4[c0+16*j] = a[4+j];
    }
    __syncthreads();
    #pragma unroll 1
    for (int row=0;row<16;row++){
      float kd = kfL[row*260 + g*64 + d];
      ks += kd;
      const float4* vp4 = (const float4*)(vhL + row*260 + g*64);
      #pragma unroll
      for (int e4=0;e4<16;e4++){
        float4 vv = vp4[e4];
        acc[4*e4]   += kd*vv.x;
        acc[4*e4+1] += kd*vv.y;
        acc[4*e4+2] += kd*vv.z;
        acc[4*e4+3] += kd*vv.w;
      }
    }
    __syncthreads();
  }
  float* kvp = kvbuf + (size_t)(b*Hz+g)*4160;
  #pragma unroll 1
  for (int e=0;e<64;e++) atomicAdd(&kvp[e*64+d], acc[e]);
  atomicAdd(&kvp[4096+d], ks);
}

// q projection (Wqkv cols 0..256) + rope/elu + linear attention + Wo + residual.
// grid: (394, Bz), 256 threads.
__global__ __launch_bounds__(256) void k_att(
    float* __restrict__ h, const float* __restrict__ Wq768,
    const float* __restrict__ kvbuf, const float* __restrict__ Wo,
    const float* __restrict__ cost, const float* __restrict__ sint){
  __shared__ float smem[12752];
  float* hrowL = smem;           // 16 x 260 (aliased as attL after q GEMM)
  float* attL  = smem;
  float* qfL   = smem + 4160;    // 16 x 260
  float* kvT   = smem + 8320;    // 64 x 68
  float* ksumL = smem + 12672;   // 64
  float* zL    = smem + 12736;   // 16
  int t = threadIdx.x;
  int b = blockIdx.y, row0 = blockIdx.x*16;
  float* hb = h + (size_t)b*Nz*Dz;
  int r = t>>4, c0 = t&15;
  for (int i=t;i<16*Dz;i+=256){ int rr=i>>8,c=i&255; int n=row0+rr; hrowL[rr*260+c] = (n<Nz)? hb[(size_t)n*Dz+c] : 0.f; }
  __syncthreads();
  {
    float4 a[4];
    #pragma unroll
    for (int j=0;j<4;j++) a[j]=f4z();
    const float4* h4 = (const float4*)(hrowL) + r*65;
    for (int kk4=0;kk4<64;kk4++){
      float4 hv = h4[kk4];
      const float4* w0 = (const float4*)(Wq768 + (size_t)(kk4*4+0)*768);
      const float4* w1 = (const float4*)(Wq768 + (size_t)(kk4*4+1)*768);
      const float4* w2 = (const float4*)(Wq768 + (size_t)(kk4*4+2)*768);
      const float4* w3 = (const float4*)(Wq768 + (size_t)(kk4*4+3)*768);
      #pragma unroll
      for (int j=0;j<4;j++){
        fma4(a[j], hv.x, w0[c0+16*j]);
        fma4(a[j], hv.y, w1[c0+16*j]);
        fma4(a[j], hv.z, w2[c0+16*j]);
        fma4(a[j], hv.w, w3[c0+16*j]);
      }
    }
    int n = row0 + r; int nc = (n<Nz)? n : 0;
    float4* qf4 = (float4*)(qfL) + r*65;
    #pragma unroll
    for (int j=0;j<4;j++){
      float4 qin = a[j];
      int wb = (c0+16*j)*4;
      int fi = (wb&63)>>1;
      float co0 = cost[nc*32+fi],   si0 = sint[nc*32+fi];
      float co1 = cost[nc*32+fi+1], si1 = sint[nc*32+fi+1];
      float4 qo;
      qo.x = elu1(qin.x*co0 - qin.y*si0);
      qo.y = elu1(qin.x*si0 + qin.y*co0);
      qo.z = elu1(qin.z*co1 - qin.w*si1);
      qo.w = elu1(qin.z*si1 + qin.w*co1);
      qf4[c0+16*j] = qo;
    }
  }
  __syncthreads();   // qfL ready; hrowL free from here
  for (int hh=0; hh<Hz; hh++){
    const float* kvp = kvbuf + (size_t)(b*Hz+hh)*4160;
    for (int i=t;i<4096;i+=256) kvT[(i>>6)*68 + (i&63)] = kvp[i];
    if (t<64) ksumL[t] = kvp[4096+t];
    __syncthreads();
    if (t<16){
      float s = 0.f;
      for (int dd=0;dd<64;dd++) s += qfL[t*260 + hh*64 + dd]*ksumL[dd];
      zL[t] = 1.f/(s + 1e-6f);
    }
    float a0=0.f,a1=0.f,a2=0.f,a3=0.f;
    const float4* q4 = (const float4*)(qfL) + r*65 + hh*16;
    const float4* kv4 = (const float4*)kvT;
    for (int d4=0; d4<16; d4++){
      float4 qv = q4[d4];
      a0 += dot4(qv, kv4[(c0   )*17 + d4]);
      a1 += dot4(qv, kv4[(c0+16)*17 + d4]);
      a2 += dot4(qv, kv4[(c0+32)*17 + d4]);
      a3 += dot4(qv, kv4[(c0+48)*17 + d4]);
    }
    __syncthreads();   // zL visible; all kvT/ksumL reads done
    float z = zL[r];
    attL[r*260 + hh*64 + c0   ] = a0*z;
    attL[r*260 + hh*64 + c0+16] = a1*z;
    attL[r*260 + hh*64 + c0+32] = a2*z;
    attL[r*260 + hh*64 + c0+48] = a3*z;
  }
  __syncthreads();
  float4 acc[4]; acc[0]=f4z(); acc[1]=f4z(); acc[2]=f4z(); acc[3]=f4z();
  for (int kk=0; kk<Dz; kk++){
    float av = attL[r*260+kk];
    const float4* wr = (const float4*)(Wo + (size_t)kk*Dz);
    fma4(acc[0], av, wr[c0]); fma4(acc[1], av, wr[c0+16]);
    fma4(acc[2], av, wr[c0+32]); fma4(acc[3], av, wr[c0+48]);
  }
  int n = row0+r;
  if (n < Nz){
    float4* hp = (float4*)(hb + (size_t)n*Dz);
    #pragma unroll
    for (int j=0;j<4;j++){
      float4 hv = hp[c0+16*j];
      hv.x += acc[j].x; hv.y += acc[j].y; hv.z += acc[j].z; hv.w += acc[j].w;
      hp[c0+16*j] = hv;
    }
  }
}

__global__ __launch_bounds__(256) void k_wkv(const float* __restrict__ h,
    const float* __restrict__ Wwk, const float* __restrict__ Wwv,
    float* __restrict__ wkbuf, float* __restrict__ wvbuf){
  __shared__ float wtL[16*257];
  int t = threadIdx.x;
  int b = blockIdx.y, m0 = blockIdx.x*16;
  const float* hb = h + ((size_t)b*Nz + (Nz-64))*Dz;
  for (int i=t;i<16*Dz;i+=256){ int r=i>>8,c=i&255; wtL[r*257+c] = hb[(size_t)(m0+r)*Dz + c]; }
  __syncthreads();
  int r=t>>4, c0=t&15;
  float4 ak0=f4z(),ak1=f4z(),av0=f4z(),av1=f4z();
  for (int kk=0;kk<Dz;kk++){
    float hv = wtL[r*257+kk];
    const float4* wk4 = (const float4*)(Wwk + (size_t)kk*DCz);
    const float4* wv4 = (const float4*)(Wwv + (size_t)kk*DCz);
    fma4(ak0,hv,wk4[c0]); fma4(ak1,hv,wk4[c0+16]);
    fma4(av0,hv,wv4[c0]); fma4(av1,hv,wv4[c0+16]);
  }
  float4* ok = (float4*)(wkbuf + (size_t)(b*64 + m0+r)*DCz);
  float4* ov = (float4*)(wvbuf + (size_t)(b*64 + m0+r)*DCz);
  ok[c0]=ak0; ok[c0+16]=ak1; ov[c0]=av0; ov[c0+16]=av1;
}

__global__ __launch_bounds__(256) void k_cache_upd(float* __restrict__ cache,
    const float* __restrict__ wkbuf, const float* __restrict__ wvbuf,
    const float* __restrict__ Wwg, const float* __restrict__ bwg,
    int s0, int it, int pas){
  __shared__ float sqL[16*132];
  __shared__ float wkL[64*132];
  __shared__ float wat[16*68];
  __shared__ float ncL[16*132];
  __shared__ float wg[16];
  int t = threadIdx.x; int b = blockIdx.x;
  for (int i=t;i<16*DCz;i+=256){ int k2=i>>7,c=i&127; sqL[k2*132+c] = cache[((size_t)(b*NSLOTz)+s0+k2)*DSLOTz + c]; }
  for (int i=t;i<64*DCz;i+=256){ int m=i>>7,c=i&127; wkL[m*132+c] = wkbuf[(size_t)(b*64+m)*DCz+c]; }
  __syncthreads();
  {
    int k2 = t>>4;
    const float4* s4 = (const float4*)(sqL) + k2*33;
    for (int mm=0;mm<4;mm++){
      int m = (t&15) + 16*mm;
      const float4* k4 = (const float4*)(wkL) + m*33;
      float a=0.f;
      for (int d4=0;d4<32;d4++) a += dot4(s4[d4], k4[d4]);
      wat[k2*68+m] = a * 0.088388347648318447f;
    }
  }
  __syncthreads();
  if (t<16){
    float mx=-1e30f;
    for (int m=0;m<64;m++) mx = fmaxf(mx, wat[t*68+m]);
    float su=0.f;
    for (int m=0;m<64;m++){ float e=__expf(wat[t*68+m]-mx); wat[t*68+m]=e; su+=e; }
    float inv=1.f/su;
    for (int m=0;m<64;m++) wat[t*68+m]*=inv;
  }
  __syncthreads();
  {
    int k2=t>>4, c0=t&15;
    float4 a0=f4z(), a1=f4z();
    const float4* wvg = (const float4*)(wvbuf + (size_t)b*64*DCz);
    for (int m=0;m<64;m++){
      float a = wat[k2*68+m];
      fma4(a0,a,wvg[m*32+c0]); fma4(a1,a,wvg[m*32+c0+16]);
    }
    ((float4*)ncL)[k2*33+c0]=a0; ((float4*)ncL)[k2*33+16+c0]=a1;
  }
  __syncthreads();
  if (t<16){
    float a = bwg[0];
    for (int d2=0; d2<DCz; d2++) a += sqL[t*132+d2]*Wwg[d2] + ncL[t*132+d2]*Wwg[DCz+d2];
    wg[t] = sigm(a);
  }
  __syncthreads();
  for (int i=t;i<16*DCz;i+=256){
    int k2=i>>7,c=i&127;
    cache[((size_t)(b*NSLOTz)+s0+k2)*DSLOTz + c] = sqL[k2*132+c] + wg[k2]*ncL[k2*132+c];
  }
  if (t<16){
    float* cp = cache + ((size_t)(b*NSLOTz)+s0+t)*DSLOTz;
    cp[128] = wg[t];
    cp[137] = (it==0)?1.f:0.f; cp[138] = (it==1)?1.f:0.f; cp[139]=0.f; cp[140]=0.f;
    cp[141] = (pas==0)?1.f:0.f; cp[142] = (pas==1)?1.f:0.f; cp[143]=0.f; cp[144]=0.f;
  }
}

__global__ __launch_bounds__(256) void k_logits(const float* __restrict__ h,
    const float* __restrict__ Wout, const float* __restrict__ bout, float* __restrict__ out){
  __shared__ float hl[16*257];
  int t = threadIdx.x; int row0 = blockIdx.x*16;
  for (int i=t;i<16*Dz;i+=256){
    int rr=i>>8,c=i&255; int row=row0+rr; int b=row/Sz, s=row-b*Sz;
    hl[rr*257+c] = h[((size_t)b*Nz + TSz + s)*Dz + c];
  }
  __syncthreads();
  int rr = t>>4, v = t&15;
  float a = bout[v];
  for (int c=0;c<Dz;c++) a += hl[rr*257+c]*Wout[c*Vz + v];
  out[(size_t)(row0+rr)*Vz + v] = a;
}

__global__ __launch_bounds__(256) void k_feedback(float* __restrict__ h,
    const float* __restrict__ logits0, const float* __restrict__ pae,
    const float* __restrict__ Wfb, const float* __restrict__ bfb){
  __shared__ float trL[16*257];
  __shared__ float paeL[16*257];
  __shared__ int amL[16];
  int t = threadIdx.x; int b = blockIdx.y; int s0 = blockIdx.x*16;
  if (t<16){
    int s = s0+t; int am=0;
    if (s < Sz){
      const float* lg = logits0 + (size_t)(b*Sz+s)*Vz;
      float best = lg[0];
      for (int v=1;v<16;v++){ if (lg[v] > best){ best=lg[v]; am=v; } }
    }
    amL[t]=am;
  }
  for (int i=t;i<16*Dz;i+=256){
    int rr=i>>8,c=i&255; int s=s0+rr;
    trL[rr*257+c] = (s<Sz)? h[((size_t)b*Nz + TSz + s)*Dz + c] : 0.f;
  }
  __syncthreads();
  for (int i=t;i<16*Dz;i+=256){ int rr=i>>8,c=i&255; paeL[rr*257+c] = pae[(size_t)amL[rr]*Dz + c]; }
  __syncthreads();
  int r=t>>4, c0=t&15;
  float4 acc[4]; acc[0]=f4z(); acc[1]=f4z(); acc[2]=f4z(); acc[3]=f4z();
  for (int kk=0;kk<Dz;kk++){
    float xv = trL[r*257+kk];
    const float4* wr = (const float4*)(Wfb + (size_t)kk*Dz);
    fma4(acc[0],xv,wr[c0]); fma4(acc[1],xv,wr[c0+16]); fma4(acc[2],xv,wr[c0+32]); fma4(acc[3],xv,wr[c0+48]);
  }
  for (int kk=0;kk<Dz;kk++){
    float xv = paeL[r*257+kk];
    const float4* wr = (const float4*)(Wfb + (size_t)(Dz+kk)*Dz);
    fma4(acc[0],xv,wr[c0]); fma4(acc[1],xv,wr[c0+16]); fma4(acc[2],xv,wr[c0+32]); fma4(acc[3],xv,wr[c0+48]);
  }
  int s = s0+r;
  if (s < Sz){
    float* cp = h + ((size_t)b*Nz + TSz + s)*Dz;
    #pragma unroll
    for (int j=0;j<4;j++){
      float vals[4] = {acc[j].x, acc[j].y, acc[j].z, acc[j].w};
      #pragma unroll
      for (int q2=0;q2<4;q2++){
        int c = (c0+16*j)*4 + q2;
        float g = sigm(vals[q2] + bfb[c]);
        cp[c] = trL[r*257+c] + g*paeL[r*257+c];
      }
    }
  }
}

extern "C" void kernel_launch(void* const* d_in, const int* in_sizes, int n_in,
                              void* d_out, int out_size, void* d_ws, size_t ws_size,
                              hipStream_t stream){
  (void)in_sizes; (void)n_in;
  const int*   demo_in   = (const int*)d_in[0];
  const int*   demo_out  = (const int*)d_in[1];
  const int*   test_in   = (const int*)d_in[2];
  const float* token_emb = (const float*)d_in[3];
  const float* seg_emb   = (const float*)d_in[4];
  const float* slot_emb  = (const float*)d_in[5];
  const float* lid_emb   = (const float*)d_in[6];
  const float* Wq_read   = (const float*)d_in[7];
  const float* Wk_read   = (const float*)d_in[8];
  const float* Wv_read   = (const float*)d_in[9];
  const float* Wg_read   = (const float*)d_in[10];
  const float* bg_read   = (const float*)d_in[11];
  const float* Wqkv      = (const float*)d_in[12];
  const float* Wo        = (const float*)d_in[13];
  const float* Wwk       = (const float*)d_in[14];
  const float* Wwv       = (const float*)d_in[15];
  const float* Wwg       = (const float*)d_in[16];
  const float* bwg       = (const float*)d_in[17];
  const float* Wout      = (const float*)d_in[18];
  const float* bout      = (const float*)d_in[19];
  const float* pae       = (const float*)d_in[20];
  const float* Wfb       = (const float*)d_in[21];
  const float* bfb       = (const float*)d_in[22];

  char* wsb = (char*)d_ws;
  size_t off = 0;
  auto alloc = [&](size_t bytes)->char*{
    char* p = wsb + off;
    off += (bytes + 255) & ~(size_t)255;
    return p;
  };
  float* hbuf   = (float*)alloc((size_t)Bz*Nz*Dz*4);       // 103.2 MB
  float* kread  = (float*)alloc((size_t)Bz*NSLOTz*DCz*4);
  float* vread  = (float*)alloc((size_t)Bz*NSLOTz*Dz*4);
  float* cache  = (float*)alloc((size_t)Bz*NSLOTz*DSLOTz*4);
  float* kvbuf  = (float*)alloc((size_t)Bz*Hz*4160*4);
  float* wkbuf  = (float*)alloc((size_t)Bz*64*DCz*4);
  float* wvbuf  = (float*)alloc((size_t)Bz*64*DCz*4);
  float* logits0= (float*)alloc((size_t)Bz*Sz*Vz*4);
  float* cost   = (float*)alloc((size_t)Nz*32*4);
  float* sint   = (float*)alloc((size_t)Nz*32*4);

  if (off > ws_size){
    k_sentinel<<<(out_size+255)/256, 256, 0, stream>>>((float*)d_out, out_size);
    return;
  }

  k_rope<<<(Nz*32+255)/256, 256, 0, stream>>>(cost, sint);
  k_cache_init<<<(Bz*NSLOTz*DSLOTz+255)/256, 256, 0, stream>>>(slot_emb, lid_emb, cache);

  const int KVN = Bz*Hz*4160;
  for (int pas=0; pas<2; pas++){
    k_embed<<<(Bz*Nz*64+255)/256, 256, 0, stream>>>(demo_in, demo_out, test_in, token_emb, seg_emb, hbuf);
    if (pas==1)
      k_feedback<<<dim3(57,Bz), 256, 0, stream>>>(hbuf, logits0, pae, Wfb, bfb);
    for (int l=0; l<3; l++){
      for (int it=0; it<2; it++){
        k_proj_cache<<<Bz*NSLOTz, 384, 0, stream>>>(cache,
            Wk_read + (size_t)l*DSLOTz*DCz, Wv_read + (size_t)l*DSLOTz*Dz, kread, vread);
        k_read_attn<<<dim3(394,Bz), 256, 0, stream>>>(kread, vread,
            Wq_read + (size_t)l*Dz*DCz, Wg_read + (size_t)l*Dz, bg_read + l, hbuf);
        k_zero<<<(KVN+255)/256, 256, 0, stream>>>(kvbuf, KVN);
        k_kv<<<dim3(NCH,Bz), 256, 0, stream>>>(hbuf,
            Wqkv + (size_t)l*Dz*768, cost, sint, kvbuf);
        k_att<<<dim3(394,Bz), 256, 0, stream>>>(hbuf,
            Wqkv + (size_t)l*Dz*768, kvbuf, Wo + (size_t)l*Dz*Dz, cost, sint);
        k_wkv<<<dim3(4,Bz), 256, 0, stream>>>(hbuf,
            Wwk + (size_t)l*Dz*DCz, Wwv + (size_t)l*Dz*DCz, wkbuf, wvbuf);
        k_cache_upd<<<Bz, 256, 0, stream>>>(cache, wkbuf, wvbuf,
            Wwg + (size_t)l*2*DCz, bwg + l, l*16, it, pas);
      }
    }
    float* outp = (pas==0) ? logits0 : (float*)d_out;
    k_logits<<<900, 256, 0, stream>>>(hbuf, Wout, bout, outp);
  }
}

// Round 3
// 48390.979 us; speedup vs baseline: 1.0402x; 1.0402x over previous
//
#include <hip/hip_runtime.h>
#include <math.h>

#define Bz 16
#define Sz 900
#define Vz 16
#define Dz 256
#define DCz 128
#define Hz 4
#define Nz 6300
#define TSz 5400
#define DSLOTz 145
#define NSLOTz 48
#define CHROWS 160
#define NCH 40

typedef unsigned short u16;
typedef unsigned int u32;

static __device__ __forceinline__ float sigm(float x){ return 1.0f/(1.0f+__expf(-x)); }
static __device__ __forceinline__ void fma4(float4& a, float s, float4 b){ a.x+=s*b.x; a.y+=s*b.y; a.z+=s*b.z; a.w+=s*b.w; }
static __device__ __forceinline__ float dot4(float4 a, float4 b){ return a.x*b.x + a.y*b.y + a.z*b.z + a.w*b.w; }
static __device__ __forceinline__ float4 f4z(){ float4 z; z.x=0.f; z.y=0.f; z.z=0.f; z.w=0.f; return z; }
static __device__ __forceinline__ float elu1(float x){ return x>0.f ? x+1.f : __expf(x); }

__global__ void k_sentinel(float* out, int nelem){
  int i = blockIdx.x*256 + threadIdx.x;
  if (i < nelem) out[i] = 12345.0f;
}

__global__ void k_zero(float* p, int n){
  int i = blockIdx.x*256 + threadIdx.x;
  if (i < n) p[i] = 0.f;
}

__global__ void k_rope(float* cost, float* sint){
  int i = blockIdx.x*256 + threadIdx.x;
  if (i >= Nz*32) return;
  int n = i>>5, f = i&31;
  double invd = pow(10000.0, -(double)f/32.0);
  double fr = (double)n * invd;
  cost[i] = (float)cos(fr);
  sint[i] = (float)sin(fr);
}

__global__ void k_embed(const int* __restrict__ di, const int* __restrict__ dq,
                        const int* __restrict__ ti, const float* __restrict__ temb,
                        const float* __restrict__ semb, float* __restrict__ h){
  int i = blockIdx.x*256 + threadIdx.x;   // over B*N*64 float4s
  if (i >= Bz*Nz*64) return;
  int dv = i & 63; int bn = i >> 6; int n = bn % Nz; int b = bn / Nz;
  int tok;
  if (n < TSz){
    int nd = n/1800; int r = n - nd*1800;
    tok = (r < Sz) ? di[(b*3+nd)*Sz + r] : dq[(b*3+nd)*Sz + (r-Sz)];
  } else {
    tok = ti[b*Sz + (n-TSz)];
  }
  const float4* e4 = (const float4*)(temb + (size_t)tok*Dz);
  const float4* s4 = (const float4*)semb;
  float4 v = e4[dv]; float4 s = s4[dv];
  v.x += s.x; v.y += s.y; v.z += s.z; v.w += s.w;
  ((float4*)h)[(size_t)bn*64 + dv] = v;
}

__global__ void k_cache_init(const float* __restrict__ slot_emb, const float* __restrict__ lid,
                             float* __restrict__ cache){
  int i = blockIdx.x*256 + threadIdx.x;
  if (i >= Bz*NSLOTz*DSLOTz) return;
  int c = i % DSLOTz; int sc = (i / DSLOTz) % NSLOTz; int l = sc >> 4;
  float v = 0.f;
  if (c < DCz) v = slot_emb[sc*DCz + c];
  else if (c >= 129 && c < 137) v = lid[l*8 + (c-129)];
  cache[i] = v;
}

__global__ __launch_bounds__(384) void k_proj_cache(const float* __restrict__ cache,
    const float* __restrict__ Wk, const float* __restrict__ Wv,
    float* __restrict__ kread, float* __restrict__ vread){
  __shared__ float crow[DSLOTz];
  int b = blockIdx.x / NSLOTz, sc = blockIdx.x % NSLOTz;
  int t = threadIdx.x;
  const float* cp = cache + (size_t)(b*NSLOTz+sc)*DSLOTz;
  if (t < DSLOTz) crow[t] = cp[t];
  __syncthreads();
  if (t < DCz){
    float a = 0.f;
    for (int r2=0;r2<DSLOTz;r2++) a += crow[r2]*Wk[r2*DCz + t];
    kread[(size_t)(b*NSLOTz+sc)*DCz + t] = a;
  } else {
    int d = t - DCz;
    float a = 0.f;
    for (int r2=0;r2<DSLOTz;r2++) a += crow[r2]*Wv[r2*Dz + d];
    vread[(size_t)(b*NSLOTz+sc)*Dz + d] = a;
  }
}

__global__ __launch_bounds__(256) void k_read_attn(
    const float* __restrict__ kread, const float* __restrict__ vread,
    const float* __restrict__ Wq, const float* __restrict__ Wg, const float* __restrict__ bg,
    float* __restrict__ h){
  __shared__ float sm[12560];        // phase1/2: hrow[16*257] | qL[16*132] | kL[48*132]; phase3: vL[48*256]
  __shared__ float attn_s[16*48];
  __shared__ float gate_s[16];
  float* hrow = sm;
  float* qL   = sm + 4112;
  float* kL   = sm + 6224;
  int t = threadIdx.x;
  int b = blockIdx.y, row0 = blockIdx.x*16;
  float* hb = h + (size_t)b*Nz*Dz;
  for (int i=t;i<16*Dz;i+=256){ int r=i>>8, c=i&255; int n=row0+r; hrow[r*257+c] = (n<Nz)? hb[(size_t)n*Dz+c] : 0.f; }
  for (int i=t;i<NSLOTz*DCz;i+=256){ int s=i>>7, d=i&127; kL[s*132+d] = kread[(size_t)(b*NSLOTz+s)*DCz + d]; }
  __syncthreads();
  if (t<16){
    float a=0.f;
    for (int c=0;c<Dz;c++) a += hrow[t*257+c]*Wg[c];
    gate_s[t] = sigm(a + bg[0]);
  }
  int r = t>>4, c0 = t&15;
  {
    float4 a0=f4z(), a1=f4z();
    for (int kk=0;kk<Dz;kk++){
      float hv = hrow[r*257+kk];
      const float4* wr = (const float4*)(Wq + (size_t)kk*DCz);
      fma4(a0, hv, wr[c0]); fma4(a1, hv, wr[c0+16]);
    }
    ((float4*)qL)[r*33 + c0] = a0;
    ((float4*)qL)[r*33 + 16 + c0] = a1;
  }
  __syncthreads();
  {
    int sb = c0*3;
    const float4* q4 = (const float4*)(qL) + r*33;
    for (int ss=0; ss<3; ss++){
      int s = sb+ss;
      const float4* k4 = (const float4*)(kL) + s*33;
      float a = 0.f;
      for (int d4=0; d4<32; d4++) a += dot4(q4[d4], k4[d4]);
      attn_s[r*48+s] = a * 0.088388347648318447f;
    }
  }
  __syncthreads();
  for (int i=t;i<NSLOTz*Dz;i+=256) sm[i] = vread[(size_t)b*NSLOTz*Dz + i];
  if (t<16){
    float mx = -1e30f;
    for (int s=0;s<48;s++) mx = fmaxf(mx, attn_s[t*48+s]);
    float su = 0.f;
    for (int s=0;s<48;s++){ float e = __expf(attn_s[t*48+s]-mx); attn_s[t*48+s]=e; su+=e; }
    float inv = 1.f/su;
    for (int s=0;s<48;s++) attn_s[t*48+s] *= inv;
  }
  __syncthreads();
  float4 acc[4]; acc[0]=f4z(); acc[1]=f4z(); acc[2]=f4z(); acc[3]=f4z();
  for (int s=0;s<NSLOTz;s++){
    float a = attn_s[r*48+s];
    const float4* v4 = (const float4*)(sm + s*Dz);
    fma4(acc[0], a, v4[c0]); fma4(acc[1], a, v4[c0+16]); fma4(acc[2], a, v4[c0+32]); fma4(acc[3], a, v4[c0+48]);
  }
  int n = row0+r;
  if (n < Nz){
    float g = gate_s[r];
    float4* hp = (float4*)(hb + (size_t)n*Dz);
    #pragma unroll
    for (int j=0;j<4;j++){
      float4 hv = hp[c0+16*j];
      hv.x += g*acc[j].x; hv.y += g*acc[j].y; hv.z += g*acc[j].z; hv.w += g*acc[j].w;
      hp[c0+16*j] = hv;
    }
  }
}

// k/v projection (Wqkv cols 256..768) + rope/elu on k + fused kv-state accumulation.
// grid: (NCH, Bz), 256 threads. Accumulates into kvbuf[(b*H+h)*4160] via atomics.
__global__ __launch_bounds__(256) void k_kv(const float* __restrict__ h,
    const float* __restrict__ Wl, const float* __restrict__ cost, const float* __restrict__ sint,
    float* __restrict__ kvbuf){
  __shared__ float smem[12480];
  float* hrowL = smem;          // 16 x 260
  float* kfL   = smem + 4160;   // 16 x 260
  float* vhL   = smem + 8320;   // 16 x 260
  int t = threadIdx.x;
  int ch = blockIdx.x, b = blockIdx.y;
  int nbase = ch*CHROWS;
  int nend = nbase + CHROWS; if (nend > Nz) nend = Nz;
  const float* hb = h + (size_t)b*Nz*Dz;
  int r = t>>4, c0 = t&15;
  int g = t>>6, d = t&63;
  float acc[64];
  #pragma unroll
  for (int e=0;e<64;e++) acc[e] = 0.f;
  float ks = 0.f;
  for (int n0 = nbase; n0 < nend; n0 += 16){
    for (int i=t;i<16*Dz;i+=256){ int rr=i>>8, c=i&255; int n=n0+rr; hrowL[rr*260+c] = (n<Nz)? hb[(size_t)n*Dz+c] : 0.f; }
    __syncthreads();
    float4 a[8];
    #pragma unroll
    for (int j=0;j<8;j++) a[j]=f4z();
    const float4* h4 = (const float4*)(hrowL) + r*65;
    for (int kk4=0;kk4<64;kk4++){
      float4 hv = h4[kk4];
      const float4* w0 = (const float4*)(Wl + (size_t)(kk4*4+0)*768 + 256);
      const float4* w1 = (const float4*)(Wl + (size_t)(kk4*4+1)*768 + 256);
      const float4* w2 = (const float4*)(Wl + (size_t)(kk4*4+2)*768 + 256);
      const float4* w3 = (const float4*)(Wl + (size_t)(kk4*4+3)*768 + 256);
      #pragma unroll
      for (int j=0;j<8;j++){
        fma4(a[j], hv.x, w0[c0+16*j]);
        fma4(a[j], hv.y, w1[c0+16*j]);
        fma4(a[j], hv.z, w2[c0+16*j]);
        fma4(a[j], hv.w, w3[c0+16*j]);
      }
    }
    int n = n0 + r;
    int valid = (n < nend);
    int nc = valid ? n : 0;
    float4* kf4 = (float4*)(kfL) + r*65;
    float4* vh4 = (float4*)(vhL) + r*65;
    #pragma unroll
    for (int j=0;j<4;j++){
      float4 kin = a[j];
      int wb = (c0+16*j)*4;          // col within 256-wide k block
      int fi = (wb&63)>>1;
      float co0 = cost[nc*32+fi],   si0 = sint[nc*32+fi];
      float co1 = cost[nc*32+fi+1], si1 = sint[nc*32+fi+1];
      float r0 = kin.x*co0 - kin.y*si0;
      float r1 = kin.x*si0 + kin.y*co0;
      float r2 = kin.z*co1 - kin.w*si1;
      float r3 = kin.z*si1 + kin.w*co1;
      float4 ko;
      ko.x = valid ? elu1(r0) : 0.f;
      ko.y = valid ? elu1(r1) : 0.f;
      ko.z = valid ? elu1(r2) : 0.f;
      ko.w = valid ? elu1(r3) : 0.f;
      kf4[c0+16*j] = ko;
      vh4[c0+16*j] = a[4+j];
    }
    __syncthreads();
    #pragma unroll 1
    for (int row=0;row<16;row++){
      float kd = kfL[row*260 + g*64 + d];
      ks += kd;
      const float4* vp4 = (const float4*)(vhL + row*260 + g*64);
      #pragma unroll
      for (int e4=0;e4<16;e4++){
        float4 vv = vp4[e4];
        acc[4*e4]   += kd*vv.x;
        acc[4*e4+1] += kd*vv.y;
        acc[4*e4+2] += kd*vv.z;
        acc[4*e4+3] += kd*vv.w;
      }
    }
    __syncthreads();
  }
  float* kvp = kvbuf + (size_t)(b*Hz+g)*4160;
  // FULLY unrolled: dynamic acc[e] indexing in a rolled loop demoted acc[] to
  // scratch (round 2: WRITE_SIZE 478MB, 42ms). Static indices keep it in VGPRs.
  #pragma unroll
  for (int e=0;e<64;e++) atomicAdd(&kvp[e*64+d], acc[e]);
  atomicAdd(&kvp[4096+d], ks);
}

// q projection (Wqkv cols 0..256) + rope/elu + linear attention + Wo + residual.
// grid: (394, Bz), 256 threads.
__global__ __launch_bounds__(256) void k_att(
    float* __restrict__ h, const float* __restrict__ Wq768,
    const float* __restrict__ kvbuf, const float* __restrict__ Wo,
    const float* __restrict__ cost, const float* __restrict__ sint){
  __shared__ float smem[12752];
  float* hrowL = smem;           // 16 x 260 (aliased as attL after q GEMM)
  float* attL  = smem;
  float* qfL   = smem + 4160;    // 16 x 260
  float* kvT   = smem + 8320;    // 64 x 68
  float* ksumL = smem + 12672;   // 64
  float* zL    = smem + 12736;   // 16
  int t = threadIdx.x;
  int b = blockIdx.y, row0 = blockIdx.x*16;
  float* hb = h + (size_t)b*Nz*Dz;
  int r = t>>4, c0 = t&15;
  for (int i=t;i<16*Dz;i+=256){ int rr=i>>8,c=i&255; int n=row0+rr; hrowL[rr*260+c] = (n<Nz)? hb[(size_t)n*Dz+c] : 0.f; }
  __syncthreads();
  {
    float4 a[4];
    #pragma unroll
    for (int j=0;j<4;j++) a[j]=f4z();
    const float4* h4 = (const float4*)(hrowL) + r*65;
    for (int kk4=0;kk4<64;kk4++){
      float4 hv = h4[kk4];
      const float4* w0 = (const float4*)(Wq768 + (size_t)(kk4*4+0)*768);
      const float4* w1 = (const float4*)(Wq768 + (size_t)(kk4*4+1)*768);
      const float4* w2 = (const float4*)(Wq768 + (size_t)(kk4*4+2)*768);
      const float4* w3 = (const float4*)(Wq768 + (size_t)(kk4*4+3)*768);
      #pragma unroll
      for (int j=0;j<4;j++){
        fma4(a[j], hv.x, w0[c0+16*j]);
        fma4(a[j], hv.y, w1[c0+16*j]);
        fma4(a[j], hv.z, w2[c0+16*j]);
        fma4(a[j], hv.w, w3[c0+16*j]);
      }
    }
    int n = row0 + r; int nc = (n<Nz)? n : 0;
    float4* qf4 = (float4*)(qfL) + r*65;
    #pragma unroll
    for (int j=0;j<4;j++){
      float4 qin = a[j];
      int wb = (c0+16*j)*4;
      int fi = (wb&63)>>1;
      float co0 = cost[nc*32+fi],   si0 = sint[nc*32+fi];
      float co1 = cost[nc*32+fi+1], si1 = sint[nc*32+fi+1];
      float4 qo;
      qo.x = elu1(qin.x*co0 - qin.y*si0);
      qo.y = elu1(qin.x*si0 + qin.y*co0);
      qo.z = elu1(qin.z*co1 - qin.w*si1);
      qo.w = elu1(qin.z*si1 + qin.w*co1);
      qf4[c0+16*j] = qo;
    }
  }
  __syncthreads();   // qfL ready; hrowL free from here
  for (int hh=0; hh<Hz; hh++){
    const float* kvp = kvbuf + (size_t)(b*Hz+hh)*4160;
    for (int i=t;i<4096;i+=256) kvT[(i>>6)*68 + (i&63)] = kvp[i];
    if (t<64) ksumL[t] = kvp[4096+t];
    __syncthreads();
    if (t<16){
      float s = 0.f;
      for (int dd=0;dd<64;dd++) s += qfL[t*260 + hh*64 + dd]*ksumL[dd];
      zL[t] = 1.f/(s + 1e-6f);
    }
    float a0=0.f,a1=0.f,a2=0.f,a3=0.f;
    const float4* q4 = (const float4*)(qfL) + r*65 + hh*16;
    const float4* kv4 = (const float4*)kvT;
    for (int d4=0; d4<16; d4++){
      float4 qv = q4[d4];
      a0 += dot4(qv, kv4[(c0   )*17 + d4]);
      a1 += dot4(qv, kv4[(c0+16)*17 + d4]);
      a2 += dot4(qv, kv4[(c0+32)*17 + d4]);
      a3 += dot4(qv, kv4[(c0+48)*17 + d4]);
    }
    __syncthreads();   // zL visible; all kvT/ksumL reads done
    float z = zL[r];
    attL[r*260 + hh*64 + c0   ] = a0*z;
    attL[r*260 + hh*64 + c0+16] = a1*z;
    attL[r*260 + hh*64 + c0+32] = a2*z;
    attL[r*260 + hh*64 + c0+48] = a3*z;
  }
  __syncthreads();
  float4 acc[4]; acc[0]=f4z(); acc[1]=f4z(); acc[2]=f4z(); acc[3]=f4z();
  for (int kk=0; kk<Dz; kk++){
    float av = attL[r*260+kk];
    const float4* wr = (const float4*)(Wo + (size_t)kk*Dz);
    fma4(acc[0], av, wr[c0]); fma4(acc[1], av, wr[c0+16]);
    fma4(acc[2], av, wr[c0+32]); fma4(acc[3], av, wr[c0+48]);
  }
  int n = row0+r;
  if (n < Nz){
    float4* hp = (float4*)(hb + (size_t)n*Dz);
    #pragma unroll
    for (int j=0;j<4;j++){
      float4 hv = hp[c0+16*j];
      hv.x += acc[j].x; hv.y += acc[j].y; hv.z += acc[j].z; hv.w += acc[j].w;
      hp[c0+16*j] = hv;
    }
  }
}

__global__ __launch_bounds__(256) void k_wkv(const float* __restrict__ h,
    const float* __restrict__ Wwk, const float* __restrict__ Wwv,
    float* __restrict__ wkbuf, float* __restrict__ wvbuf){
  __shared__ float wtL[16*257];
  int t = threadIdx.x;
  int b = blockIdx.y, m0 = blockIdx.x*16;
  const float* hb = h + ((size_t)b*Nz + (Nz-64))*Dz;
  for (int i=t;i<16*Dz;i+=256){ int r=i>>8,c=i&255; wtL[r*257+c] = hb[(size_t)(m0+r)*Dz + c]; }
  __syncthreads();
  int r=t>>4, c0=t&15;
  float4 ak0=f4z(),ak1=f4z(),av0=f4z(),av1=f4z();
  for (int kk=0;kk<Dz;kk++){
    float hv = wtL[r*257+kk];
    const float4* wk4 = (const float4*)(Wwk + (size_t)kk*DCz);
    const float4* wv4 = (const float4*)(Wwv + (size_t)kk*DCz);
    fma4(ak0,hv,wk4[c0]); fma4(ak1,hv,wk4[c0+16]);
    fma4(av0,hv,wv4[c0]); fma4(av1,hv,wv4[c0+16]);
  }
  float4* ok = (float4*)(wkbuf + (size_t)(b*64 + m0+r)*DCz);
  float4* ov = (float4*)(wvbuf + (size_t)(b*64 + m0+r)*DCz);
  ok[c0]=ak0; ok[c0+16]=ak1; ov[c0]=av0; ov[c0+16]=av1;
}

__global__ __launch_bounds__(256) void k_cache_upd(float* __restrict__ cache,
    const float* __restrict__ wkbuf, const float* __restrict__ wvbuf,
    const float* __restrict__ Wwg, const float* __restrict__ bwg,
    int s0, int it, int pas){
  __shared__ float sqL[16*132];
  __shared__ float wkL[64*132];
  __shared__ float wat[16*68];
  __shared__ float ncL[16*132];
  __shared__ float wg[16];
  int t = threadIdx.x; int b = blockIdx.x;
  for (int i=t;i<16*DCz;i+=256){ int k2=i>>7,c=i&127; sqL[k2*132+c] = cache[((size_t)(b*NSLOTz)+s0+k2)*DSLOTz + c]; }
  for (int i=t;i<64*DCz;i+=256){ int m=i>>7,c=i&127; wkL[m*132+c] = wkbuf[(size_t)(b*64+m)*DCz+c]; }
  __syncthreads();
  {
    int k2 = t>>4;
    const float4* s4 = (const float4*)(sqL) + k2*33;
    for (int mm=0;mm<4;mm++){
      int m = (t&15) + 16*mm;
      const float4* k4 = (const float4*)(wkL) + m*33;
      float a=0.f;
      for (int d4=0;d4<32;d4++) a += dot4(s4[d4], k4[d4]);
      wat[k2*68+m] = a * 0.088388347648318447f;
    }
  }
  __syncthreads();
  if (t<16){
    float mx=-1e30f;
    for (int m=0;m<64;m++) mx = fmaxf(mx, wat[t*68+m]);
    float su=0.f;
    for (int m=0;m<64;m++){ float e=__expf(wat[t*68+m]-mx); wat[t*68+m]=e; su+=e; }
    float inv=1.f/su;
    for (int m=0;m<64;m++) wat[t*68+m]*=inv;
  }
  __syncthreads();
  {
    int k2=t>>4, c0=t&15;
    float4 a0=f4z(), a1=f4z();
    const float4* wvg = (const float4*)(wvbuf + (size_t)b*64*DCz);
    for (int m=0;m<64;m++){
      float a = wat[k2*68+m];
      fma4(a0,a,wvg[m*32+c0]); fma4(a1,a,wvg[m*32+c0+16]);
    }
    ((float4*)ncL)[k2*33+c0]=a0; ((float4*)ncL)[k2*33+16+c0]=a1;
  }
  __syncthreads();
  if (t<16){
    float a = bwg[0];
    for (int d2=0; d2<DCz; d2++) a += sqL[t*132+d2]*Wwg[d2] + ncL[t*132+d2]*Wwg[DCz+d2];
    wg[t] = sigm(a);
  }
  __syncthreads();
  for (int i=t;i<16*DCz;i+=256){
    int k2=i>>7,c=i&127;
    cache[((size_t)(b*NSLOTz)+s0+k2)*DSLOTz + c] = sqL[k2*132+c] + wg[k2]*ncL[k2*132+c];
  }
  if (t<16){
    float* cp = cache + ((size_t)(b*NSLOTz)+s0+t)*DSLOTz;
    cp[128] = wg[t];
    cp[137] = (it==0)?1.f:0.f; cp[138] = (it==1)?1.f:0.f; cp[139]=0.f; cp[140]=0.f;
    cp[141] = (pas==0)?1.f:0.f; cp[142] = (pas==1)?1.f:0.f; cp[143]=0.f; cp[144]=0.f;
  }
}

__global__ __launch_bounds__(256) void k_logits(const float* __restrict__ h,
    const float* __restrict__ Wout, const float* __restrict__ bout, float* __restrict__ out){
  __shared__ float hl[16*257];
  int t = threadIdx.x; int row0 = blockIdx.x*16;
  for (int i=t;i<16*Dz;i+=256){
    int rr=i>>8,c=i&255; int row=row0+rr; int b=row/Sz, s=row-b*Sz;
    hl[rr*257+c] = h[((size_t)b*Nz + TSz + s)*Dz + c];
  }
  __syncthreads();
  int rr = t>>4, v = t&15;
  float a = bout[v];
  for (int c=0;c<Dz;c++) a += hl[rr*257+c]*Wout[c*Vz + v];
  out[(size_t)(row0+rr)*Vz + v] = a;
}

__global__ __launch_bounds__(256) void k_feedback(float* __restrict__ h,
    const float* __restrict__ logits0, const float* __restrict__ pae,
    const float* __restrict__ Wfb, const float* __restrict__ bfb){
  __shared__ float trL[16*257];
  __shared__ float paeL[16*257];
  __shared__ int amL[16];
  int t = threadIdx.x; int b = blockIdx.y; int s0 = blockIdx.x*16;
  if (t<16){
    int s = s0+t; int am=0;
    if (s < Sz){
      const float* lg = logits0 + (size_t)(b*Sz+s)*Vz;
      float best = lg[0];
      for (int v=1;v<16;v++){ if (lg[v] > best){ best=lg[v]; am=v; } }
    }
    amL[t]=am;
  }
  for (int i=t;i<16*Dz;i+=256){
    int rr=i>>8,c=i&255; int s=s0+rr;
    trL[rr*257+c] = (s<Sz)? h[((size_t)b*Nz + TSz + s)*Dz + c] : 0.f;
  }
  __syncthreads();
  for (int i=t;i<16*Dz;i+=256){ int rr=i>>8,c=i&255; paeL[rr*257+c] = pae[(size_t)amL[rr]*Dz + c]; }
  __syncthreads();
  int r=t>>4, c0=t&15;
  float4 acc[4]; acc[0]=f4z(); acc[1]=f4z(); acc[2]=f4z(); acc[3]=f4z();
  for (int kk=0;kk<Dz;kk++){
    float xv = trL[r*257+kk];
    const float4* wr = (const float4*)(Wfb + (size_t)kk*Dz);
    fma4(acc[0],xv,wr[c0]); fma4(acc[1],xv,wr[c0+16]); fma4(acc[2],xv,wr[c0+32]); fma4(acc[3],xv,wr[c0+48]);
  }
  for (int kk=0;kk<Dz;kk++){
    float xv = paeL[r*257+kk];
    const float4* wr = (const float4*)(Wfb + (size_t)(Dz+kk)*Dz);
    fma4(acc[0],xv,wr[c0]); fma4(acc[1],xv,wr[c0+16]); fma4(acc[2],xv,wr[c0+32]); fma4(acc[3],xv,wr[c0+48]);
  }
  int s = s0+r;
  if (s < Sz){
    float* cp = h + ((size_t)b*Nz + TSz + s)*Dz;
    #pragma unroll
    for (int j=0;j<4;j++){
      float vals[4] = {acc[j].x, acc[j].y, acc[j].z, acc[j].w};
      #pragma unroll
      for (int q2=0;q2<4;q2++){
        int c = (c0+16*j)*4 + q2;
        float g = sigm(vals[q2] + bfb[c]);
        cp[c] = trL[r*257+c] + g*paeL[r*257+c];
      }
    }
  }
}

extern "C" void kernel_launch(void* const* d_in, const int* in_sizes, int n_in,
                              void* d_out, int out_size, void* d_ws, size_t ws_size,
                              hipStream_t stream){
  (void)in_sizes; (void)n_in;
  const int*   demo_in   = (const int*)d_in[0];
  const int*   demo_out  = (const int*)d_in[1];
  const int*   test_in   = (const int*)d_in[2];
  const float* token_emb = (const float*)d_in[3];
  const float* seg_emb   = (const float*)d_in[4];
  const float* slot_emb  = (const float*)d_in[5];
  const float* lid_emb   = (const float*)d_in[6];
  const float* Wq_read   = (const float*)d_in[7];
  const float* Wk_read   = (const float*)d_in[8];
  const float* Wv_read   = (const float*)d_in[9];
  const float* Wg_read   = (const float*)d_in[10];
  const float* bg_read   = (const float*)d_in[11];
  const float* Wqkv      = (const float*)d_in[12];
  const float* Wo        = (const float*)d_in[13];
  const float* Wwk       = (const float*)d_in[14];
  const float* Wwv       = (const float*)d_in[15];
  const float* Wwg       = (const float*)d_in[16];
  const float* bwg       = (const float*)d_in[17];
  const float* Wout      = (const float*)d_in[18];
  const float* bout      = (const float*)d_in[19];
  const float* pae       = (const float*)d_in[20];
  const float* Wfb       = (const float*)d_in[21];
  const float* bfb       = (const float*)d_in[22];

  char* wsb = (char*)d_ws;
  size_t off = 0;
  auto alloc = [&](size_t bytes)->char*{
    char* p = wsb + off;
    off += (bytes + 255) & ~(size_t)255;
    return p;
  };
  float* hbuf   = (float*)alloc((size_t)Bz*Nz*Dz*4);       // 103.2 MB
  float* kread  = (float*)alloc((size_t)Bz*NSLOTz*DCz*4);
  float* vread  = (float*)alloc((size_t)Bz*NSLOTz*Dz*4);
  float* cache  = (float*)alloc((size_t)Bz*NSLOTz*DSLOTz*4);
  float* kvbuf  = (float*)alloc((size_t)Bz*Hz*4160*4);
  float* wkbuf  = (float*)alloc((size_t)Bz*64*DCz*4);
  float* wvbuf  = (float*)alloc((size_t)Bz*64*DCz*4);
  float* logits0= (float*)alloc((size_t)Bz*Sz*Vz*4);
  float* cost   = (float*)alloc((size_t)Nz*32*4);
  float* sint   = (float*)alloc((size_t)Nz*32*4);

  if (off > ws_size){
    k_sentinel<<<(out_size+255)/256, 256, 0, stream>>>((float*)d_out, out_size);
    return;
  }

  k_rope<<<(Nz*32+255)/256, 256, 0, stream>>>(cost, sint);
  k_cache_init<<<(Bz*NSLOTz*DSLOTz+255)/256, 256, 0, stream>>>(slot_emb, lid_emb, cache);

  const int KVN = Bz*Hz*4160;
  for (int pas=0; pas<2; pas++){
    k_embed<<<(Bz*Nz*64+255)/256, 256, 0, stream>>>(demo_in, demo_out, test_in, token_emb, seg_emb, hbuf);
    if (pas==1)
      k_feedback<<<dim3(57,Bz), 256, 0, stream>>>(hbuf, logits0, pae, Wfb, bfb);
    for (int l=0; l<3; l++){
      for (int it=0; it<2; it++){
        k_proj_cache<<<Bz*NSLOTz, 384, 0, stream>>>(cache,
            Wk_read + (size_t)l*DSLOTz*DCz, Wv_read + (size_t)l*DSLOTz*Dz, kread, vread);
        k_read_attn<<<dim3(394,Bz), 256, 0, stream>>>(kread, vread,
            Wq_read + (size_t)l*Dz*DCz, Wg_read + (size_t)l*Dz, bg_read + l, hbuf);
        k_zero<<<(KVN+255)/256, 256, 0, stream>>>(kvbuf, KVN);
        k_kv<<<dim3(NCH,Bz), 256, 0, stream>>>(hbuf,
            Wqkv + (size_t)l*Dz*768, cost, sint, kvbuf);
        k_att<<<dim3(394,Bz), 256, 0, stream>>>(hbuf,
            Wqkv + (size_t)l*Dz*768, kvbuf, Wo + (size_t)l*Dz*Dz, cost, sint);
        k_wkv<<<dim3(4,Bz), 256, 0, stream>>>(hbuf,
            Wwk + (size_t)l*Dz*DCz, Wwv + (size_t)l*Dz*DCz, wkbuf, wvbuf);
        k_cache_upd<<<Bz, 256, 0, stream>>>(cache, wkbuf, wvbuf,
            Wwg + (size_t)l*2*DCz, bwg + l, l*16, it, pas);
      }
    }
    float* outp = (pas==0) ? logits0 : (float*)d_out;
    k_logits<<<900, 256, 0, stream>>>(hbuf, Wout, bout, outp);
  }
}

// Round 4
// 20542.780 us; speedup vs baseline: 2.4504x; 2.3556x over previous
//
#include <hip/hip_runtime.h>
#include <math.h>

#define Bz 16
#define Sz 900
#define Vz 16
#define Dz 256
#define DCz 128
#define Hz 4
#define Nz 6300
#define TSz 5400
#define DSLOTz 145
#define NSLOTz 48
#define GXA 99   // ceil(6300/64) row-blocks for k_kv/k_att

typedef unsigned short u16;
typedef unsigned int u32;

static __device__ __forceinline__ float sigm(float x){ return 1.0f/(1.0f+__expf(-x)); }
static __device__ __forceinline__ void fma4(float4& a, float s, float4 b){ a.x+=s*b.x; a.y+=s*b.y; a.z+=s*b.z; a.w+=s*b.w; }
static __device__ __forceinline__ float dot4(float4 a, float4 b){ return a.x*b.x + a.y*b.y + a.z*b.z + a.w*b.w; }
static __device__ __forceinline__ float4 f4z(){ float4 z; z.x=0.f; z.y=0.f; z.z=0.f; z.w=0.f; return z; }
static __device__ __forceinline__ float elu1(float x){ return x>0.f ? x+1.f : __expf(x); }
static __device__ __forceinline__ float fcomp(float4 v, int i){ return (i==0)?v.x:(i==1)?v.y:(i==2)?v.z:v.w; }

__global__ void k_sentinel(float* out, int nelem){
  int i = blockIdx.x*256 + threadIdx.x;
  if (i < nelem) out[i] = 12345.0f;
}

__global__ void k_zero(float* p, int n){
  int i = blockIdx.x*256 + threadIdx.x;
  if (i < n) p[i] = 0.f;
}

__global__ void k_rope(float* cost, float* sint){
  int i = blockIdx.x*256 + threadIdx.x;
  if (i >= Nz*32) return;
  int n = i>>5, f = i&31;
  double invd = pow(10000.0, -(double)f/32.0);
  double fr = (double)n * invd;
  cost[i] = (float)cos(fr);
  sint[i] = (float)sin(fr);
}

__global__ void k_embed(const int* __restrict__ di, const int* __restrict__ dq,
                        const int* __restrict__ ti, const float* __restrict__ temb,
                        const float* __restrict__ semb, float* __restrict__ h){
  int i = blockIdx.x*256 + threadIdx.x;   // over B*N*64 float4s
  if (i >= Bz*Nz*64) return;
  int dv = i & 63; int bn = i >> 6; int n = bn % Nz; int b = bn / Nz;
  int tok;
  if (n < TSz){
    int nd = n/1800; int r = n - nd*1800;
    tok = (r < Sz) ? di[(b*3+nd)*Sz + r] : dq[(b*3+nd)*Sz + (r-Sz)];
  } else {
    tok = ti[b*Sz + (n-TSz)];
  }
  const float4* e4 = (const float4*)(temb + (size_t)tok*Dz);
  const float4* s4 = (const float4*)semb;
  float4 v = e4[dv]; float4 s = s4[dv];
  v.x += s.x; v.y += s.y; v.z += s.z; v.w += s.w;
  ((float4*)h)[(size_t)bn*64 + dv] = v;
}

__global__ void k_cache_init(const float* __restrict__ slot_emb, const float* __restrict__ lid,
                             float* __restrict__ cache){
  int i = blockIdx.x*256 + threadIdx.x;
  if (i >= Bz*NSLOTz*DSLOTz) return;
  int c = i % DSLOTz; int sc = (i / DSLOTz) % NSLOTz; int l = sc >> 4;
  float v = 0.f;
  if (c < DCz) v = slot_emb[sc*DCz + c];
  else if (c >= 129 && c < 137) v = lid[l*8 + (c-129)];
  cache[i] = v;
}

__global__ __launch_bounds__(384) void k_proj_cache(const float* __restrict__ cache,
    const float* __restrict__ Wk, const float* __restrict__ Wv,
    float* __restrict__ kread, float* __restrict__ vread){
  __shared__ float crow[DSLOTz];
  int b = blockIdx.x / NSLOTz, sc = blockIdx.x % NSLOTz;
  int t = threadIdx.x;
  const float* cp = cache + (size_t)(b*NSLOTz+sc)*DSLOTz;
  if (t < DSLOTz) crow[t] = cp[t];
  __syncthreads();
  if (t < DCz){
    float a = 0.f;
    for (int r2=0;r2<DSLOTz;r2++) a += crow[r2]*Wk[r2*DCz + t];
    kread[(size_t)(b*NSLOTz+sc)*DCz + t] = a;
  } else {
    int d = t - DCz;
    float a = 0.f;
    for (int r2=0;r2<DSLOTz;r2++) a += crow[r2]*Wv[r2*Dz + d];
    vread[(size_t)(b*NSLOTz+sc)*Dz + d] = a;
  }
}

__global__ __launch_bounds__(256) void k_read_attn(
    const float* __restrict__ kread, const float* __restrict__ vread,
    const float* __restrict__ Wq, const float* __restrict__ Wg, const float* __restrict__ bg,
    float* __restrict__ h){
  __shared__ float sm[12560];        // phase1/2: hrow[16*257] | qL[16*132] | kL[48*132]; phase3: vL[48*256]
  __shared__ float attn_s[16*48];
  __shared__ float gate_s[16];
  float* hrow = sm;
  float* qL   = sm + 4112;
  float* kL   = sm + 6224;
  int t = threadIdx.x;
  int b = blockIdx.y, row0 = blockIdx.x*16;
  float* hb = h + (size_t)b*Nz*Dz;
  for (int i=t;i<16*Dz;i+=256){ int r=i>>8, c=i&255; int n=row0+r; hrow[r*257+c] = (n<Nz)? hb[(size_t)n*Dz+c] : 0.f; }
  for (int i=t;i<NSLOTz*DCz;i+=256){ int s=i>>7, d=i&127; kL[s*132+d] = kread[(size_t)(b*NSLOTz+s)*DCz + d]; }
  __syncthreads();
  if (t<16){
    float a=0.f;
    for (int c=0;c<Dz;c++) a += hrow[t*257+c]*Wg[c];
    gate_s[t] = sigm(a + bg[0]);
  }
  int r = t>>4, c0 = t&15;
  {
    float4 a0=f4z(), a1=f4z();
    for (int kk=0;kk<Dz;kk++){
      float hv = hrow[r*257+kk];
      const float4* wr = (const float4*)(Wq + (size_t)kk*DCz);
      fma4(a0, hv, wr[c0]); fma4(a1, hv, wr[c0+16]);
    }
    ((float4*)qL)[r*33 + c0] = a0;
    ((float4*)qL)[r*33 + 16 + c0] = a1;
  }
  __syncthreads();
  {
    // s = c0 + 16*ss: bank stride 33*4 floats -> 4-bank step, 2-way aliasing (free).
    // (old s = c0*3+ss had 12-bank stride -> 4-way conflicts, 3.6M SQ_LDS_BANK_CONFLICT)
    const float4* q4 = (const float4*)(qL) + r*33;
    for (int ss=0; ss<3; ss++){
      int s = c0 + 16*ss;
      const float4* k4 = (const float4*)(kL) + s*33;
      float a = 0.f;
      for (int d4=0; d4<32; d4++) a += dot4(q4[d4], k4[d4]);
      attn_s[r*48+s] = a * 0.088388347648318447f;
    }
  }
  __syncthreads();
  for (int i=t;i<NSLOTz*Dz;i+=256) sm[i] = vread[(size_t)b*NSLOTz*Dz + i];
  if (t<16){
    float mx = -1e30f;
    for (int s=0;s<48;s++) mx = fmaxf(mx, attn_s[t*48+s]);
    float su = 0.f;
    for (int s=0;s<48;s++){ float e = __expf(attn_s[t*48+s]-mx); attn_s[t*48+s]=e; su+=e; }
    float inv = 1.f/su;
    for (int s=0;s<48;s++) attn_s[t*48+s] *= inv;
  }
  __syncthreads();
  float4 acc[4]; acc[0]=f4z(); acc[1]=f4z(); acc[2]=f4z(); acc[3]=f4z();
  for (int s=0;s<NSLOTz;s++){
    float a = attn_s[r*48+s];
    const float4* v4 = (const float4*)(sm + s*Dz);
    fma4(acc[0], a, v4[c0]); fma4(acc[1], a, v4[c0+16]); fma4(acc[2], a, v4[c0+32]); fma4(acc[3], a, v4[c0+48]);
  }
  int n = row0+r;
  if (n < Nz){
    float g = gate_s[r];
    float4* hp = (float4*)(hb + (size_t)n*Dz);
    #pragma unroll
    for (int j=0;j<4;j++){
      float4 hv = hp[c0+16*j];
      hv.x += g*acc[j].x; hv.y += g*acc[j].y; hv.z += g*acc[j].z; hv.w += g*acc[j].w;
      hp[c0+16*j] = hv;
    }
  }
}

// k/v projection (Wqkv cols 256..768) + rope/elu + fused kv accumulation.
// 64-row tiles, LDS-staged weights (K-tile 32), rows/lane=4.
// LDS: wT [0,16384) 32x512; hT [16384,18560) 32x[64+4]. P2 reuses [0,8704) for kfH/vhH.
__global__ __launch_bounds__(256) void k_kv(const float* __restrict__ h,
    const float* __restrict__ Wl, const float* __restrict__ cost, const float* __restrict__ sint,
    float* __restrict__ kvbuf){
  __shared__ float smem[18560];
  const int t = threadIdx.x;
  const int b = blockIdx.y;
  const int n0 = blockIdx.x*64;
  const int c0 = t&15, rr = t>>4;
  const float* hb = h + (size_t)b*Nz*Dz;
  float4 ka[4][4], va[4][4];
  #pragma unroll
  for (int i=0;i<4;i++){
    #pragma unroll
    for (int j=0;j<4;j++){ ka[i][j]=f4z(); va[i][j]=f4z(); }
  }
  for (int kt=0; kt<256; kt+=32){
    __syncthreads();
    for (int id=t; id<4096; id+=256){
      int wr = id>>7, cf = id&127;
      ((float4*)smem)[wr*128+cf] = ((const float4*)(Wl + (size_t)(kt+wr)*768 + 256))[cf];
    }
    for (int id=t; id<512; id+=256){
      int row = id>>3, u = id&7;
      int n = n0 + row;
      float4 hv = (n<Nz) ? ((const float4*)(hb + (size_t)n*Dz))[(kt>>2)+u] : f4z();
      float* hp = smem + 16384 + row;
      hp[(4*u+0)*68]=hv.x; hp[(4*u+1)*68]=hv.y; hp[(4*u+2)*68]=hv.z; hp[(4*u+3)*68]=hv.w;
    }
    __syncthreads();
    for (int kk=0; kk<32; kk++){
      float4 hv = *(const float4*)(smem + 16384 + kk*68 + 4*rr);
      const float4* wrow = (const float4*)smem + kk*128;
      float4 wk0=wrow[c0], wk1=wrow[c0+16], wk2=wrow[c0+32], wk3=wrow[c0+48];
      float4 wv0=wrow[64+c0], wv1=wrow[64+c0+16], wv2=wrow[64+c0+32], wv3=wrow[64+c0+48];
      #pragma unroll
      for (int i=0;i<4;i++){
        float hc = fcomp(hv, i);
        fma4(ka[i][0],hc,wk0); fma4(ka[i][1],hc,wk1); fma4(ka[i][2],hc,wk2); fma4(ka[i][3],hc,wk3);
        fma4(va[i][0],hc,wv0); fma4(va[i][1],hc,wv1); fma4(va[i][2],hc,wv2); fma4(va[i][3],hc,wv3);
      }
    }
  }
  // rope + elu on k (head = j, hd = 4*c0+q, fi = 2*c0 (+1)); zero invalid rows so kv sums are clean
  #pragma unroll
  for (int i=0;i<4;i++){
    int n = n0 + 4*rr + i;
    int valid = (n < Nz);
    int nc = valid ? n : 0;
    float co0 = cost[nc*32 + 2*c0], si0 = sint[nc*32 + 2*c0];
    float co1 = cost[nc*32 + 2*c0+1], si1 = sint[nc*32 + 2*c0+1];
    #pragma unroll
    for (int j=0;j<4;j++){
      float4 kin = ka[i][j];
      float r0 = kin.x*co0 - kin.y*si0;
      float r1 = kin.x*si0 + kin.y*co0;
      float r2 = kin.z*co1 - kin.w*si1;
      float r3 = kin.z*si1 + kin.w*co1;
      float4 ko;
      ko.x = valid ? elu1(r0) : 0.f;
      ko.y = valid ? elu1(r1) : 0.f;
      ko.z = valid ? elu1(r2) : 0.f;
      ko.w = valid ? elu1(r3) : 0.f;
      ka[i][j] = ko;
    }
  }
  // P2: per head, kf/vh through LDS, outer-product accumulate, atomics to kvbuf[e*64+d]
  const int d = t&63, q4 = t>>6;
  float* kvb = kvbuf + (size_t)(b*Hz)*4160;
  #pragma unroll
  for (int g=0; g<4; g++){
    __syncthreads();
    #pragma unroll
    for (int i=0;i<4;i++){
      *(float4*)(smem + (4*rr+i)*68 + 4*c0)        = ka[i][g];
      *(float4*)(smem + 4352 + (4*rr+i)*68 + 4*c0) = va[i][g];
    }
    __syncthreads();
    float4 kvacc[4];
    #pragma unroll
    for (int u=0;u<4;u++) kvacc[u]=f4z();
    float ksl = 0.f;
    for (int row=0; row<64; row++){
      float kd = smem[row*68 + d];
      ksl += kd;
      const float4* vp = (const float4*)(smem + 4352 + row*68);
      #pragma unroll
      for (int u=0;u<4;u++) fma4(kvacc[u], kd, vp[q4*4+u]);
    }
    float* kq = kvb + g*4160;
    #pragma unroll
    for (int u=0;u<4;u++){
      int e = q4*16 + 4*u;
      atomicAdd(&kq[(e+0)*64+d], kvacc[u].x);
      atomicAdd(&kq[(e+1)*64+d], kvacc[u].y);
      atomicAdd(&kq[(e+2)*64+d], kvacc[u].z);
      atomicAdd(&kq[(e+3)*64+d], kvacc[u].w);
    }
    if (q4==0) atomicAdd(&kq[4096+d], ksl);
  }
}

// q projection + rope/elu (regs) + per-head linear attention + per-head partial Wo GEMM + residual.
// 64-row tiles. LDS (floats): P1: wT [0,8192) 32x256, hT [8192,10368) 32x[64+4].
// P2 (per head): qfH [0,4352) 64x68, kvT [4352,8704) 64x68, ksum [8704,8768), z [8768,8832),
//                attT [8832,13184) 64x68 (attT[e][row]).  P3: WoT16 [0,4096) 16x256.
__global__ __launch_bounds__(256) void k_att(
    float* __restrict__ h, const float* __restrict__ Wq768,
    const float* __restrict__ kvbuf, const float* __restrict__ Wo,
    const float* __restrict__ cost, const float* __restrict__ sint){
  __shared__ float smem[13184];
  const int t = threadIdx.x;
  const int b = blockIdx.y;
  const int n0 = blockIdx.x*64;
  const int c0 = t&15, rr = t>>4;
  float* hb = h + (size_t)b*Nz*Dz;
  float4 qa[4][4];
  #pragma unroll
  for (int i=0;i<4;i++){
    #pragma unroll
    for (int j=0;j<4;j++) qa[i][j]=f4z();
  }
  for (int kt=0; kt<256; kt+=32){
    __syncthreads();
    for (int id=t; id<2048; id+=256){
      int wr = id>>6, cf = id&63;
      ((float4*)smem)[wr*64+cf] = ((const float4*)(Wq768 + (size_t)(kt+wr)*768))[cf];
    }
    for (int id=t; id<512; id+=256){
      int row = id>>3, u = id&7;
      int n = n0 + row;
      float4 hv = (n<Nz) ? ((const float4*)(hb + (size_t)n*Dz))[(kt>>2)+u] : f4z();
      float* hp = smem + 8192 + row;
      hp[(4*u+0)*68]=hv.x; hp[(4*u+1)*68]=hv.y; hp[(4*u+2)*68]=hv.z; hp[(4*u+3)*68]=hv.w;
    }
    __syncthreads();
    for (int kk=0; kk<32; kk++){
      float4 hv = *(const float4*)(smem + 8192 + kk*68 + 4*rr);
      const float4* wrow = (const float4*)smem + kk*64;
      float4 w0=wrow[c0], w1=wrow[c0+16], w2=wrow[c0+32], w3=wrow[c0+48];
      #pragma unroll
      for (int i=0;i<4;i++){
        float hc = fcomp(hv, i);
        fma4(qa[i][0],hc,w0); fma4(qa[i][1],hc,w1); fma4(qa[i][2],hc,w2); fma4(qa[i][3],hc,w3);
      }
    }
  }
  // rope + elu on q in regs (invalid rows: garbage but never stored)
  #pragma unroll
  for (int i=0;i<4;i++){
    int n = n0 + 4*rr + i;
    int nc = (n < Nz) ? n : 0;
    float co0 = cost[nc*32 + 2*c0], si0 = sint[nc*32 + 2*c0];
    float co1 = cost[nc*32 + 2*c0+1], si1 = sint[nc*32 + 2*c0+1];
    #pragma unroll
    for (int j=0;j<4;j++){
      float4 qi = qa[i][j];
      float4 qo;
      qo.x = elu1(qi.x*co0 - qi.y*si0);
      qo.y = elu1(qi.x*si0 + qi.y*co0);
      qo.z = elu1(qi.z*co1 - qi.w*si1);
      qo.w = elu1(qi.z*si1 + qi.w*co1);
      qa[i][j] = qo;
    }
  }
  float4 oa[4][4];
  #pragma unroll
  for (int i=0;i<4;i++){
    #pragma unroll
    for (int j=0;j<4;j++) oa[i][j]=f4z();
  }
  const float* kvb = kvbuf + (size_t)(b*Hz)*4160;
  #pragma unroll
  for (int hh=0; hh<4; hh++){
    __syncthreads();
    #pragma unroll
    for (int i=0;i<4;i++) *(float4*)(smem + (4*rr+i)*68 + 4*c0) = qa[i][hh];
    const float* kvp = kvb + hh*4160;
    for (int id=t; id<1024; id+=256){
      int e = id>>4, d4 = id&15;
      float4 kv4 = ((const float4*)kvp)[id];
      float* kp = smem + 4352 + e;
      kp[(4*d4+0)*68]=kv4.x; kp[(4*d4+1)*68]=kv4.y; kp[(4*d4+2)*68]=kv4.z; kp[(4*d4+3)*68]=kv4.w;
    }
    if (t<64) smem[8704+t] = kvp[4096+t];
    __syncthreads();
    if (t<64){
      float s = 0.f;
      for (int dd=0; dd<64; dd++) s += smem[t*68+dd]*smem[8704+dd];
      smem[8768+t] = 1.f/(s + 1e-6f);
    }
    float4 aa[4];
    #pragma unroll
    for (int i=0;i<4;i++) aa[i]=f4z();
    for (int dd=0; dd<64; dd++){
      float4 kv4 = *(const float4*)(smem + 4352 + dd*68 + 4*c0);
      #pragma unroll
      for (int i=0;i<4;i++){
        float qv = smem[(4*rr+i)*68 + dd];
        fma4(aa[i], qv, kv4);
      }
    }
    __syncthreads();
    #pragma unroll
    for (int i=0;i<4;i++){
      float zv = smem[8768 + 4*rr+i];
      smem[8832 + (4*c0+0)*68 + 4*rr+i] = aa[i].x*zv;
      smem[8832 + (4*c0+1)*68 + 4*rr+i] = aa[i].y*zv;
      smem[8832 + (4*c0+2)*68 + 4*rr+i] = aa[i].z*zv;
      smem[8832 + (4*c0+3)*68 + 4*rr+i] = aa[i].w*zv;
    }
    for (int kt2=0; kt2<64; kt2+=16){
      __syncthreads();
      for (int id=t; id<1024; id+=256){
        int wr = id>>6, cf = id&63;
        ((float4*)smem)[wr*64+cf] = ((const float4*)(Wo + (size_t)(hh*64+kt2+wr)*256))[cf];
      }
      __syncthreads();
      for (int kk=0; kk<16; kk++){
        float4 av = *(const float4*)(smem + 8832 + (kt2+kk)*68 + 4*rr);
        const float4* wrow = (const float4*)smem + kk*64;
        float4 w0=wrow[c0], w1=wrow[c0+16], w2=wrow[c0+32], w3=wrow[c0+48];
        #pragma unroll
        for (int i=0;i<4;i++){
          float ac = fcomp(av, i);
          fma4(oa[i][0],ac,w0); fma4(oa[i][1],ac,w1); fma4(oa[i][2],ac,w2); fma4(oa[i][3],ac,w3);
        }
      }
    }
  }
  #pragma unroll
  for (int i=0;i<4;i++){
    int n = n0 + 4*rr + i;
    if (n < Nz){
      float4* hp = (float4*)(hb + (size_t)n*Dz);
      #pragma unroll
      for (int j=0;j<4;j++){
        float4 hv = hp[c0+16*j];
        hv.x += oa[i][j].x; hv.y += oa[i][j].y; hv.z += oa[i][j].z; hv.w += oa[i][j].w;
        hp[c0+16*j] = hv;
      }
    }
  }
}

__global__ __launch_bounds__(256) void k_wkv(const float* __restrict__ h,
    const float* __restrict__ Wwk, const float* __restrict__ Wwv,
    float* __restrict__ wkbuf, float* __restrict__ wvbuf){
  __shared__ float wtL[16*257];
  int t = threadIdx.x;
  int b = blockIdx.y, m0 = blockIdx.x*16;
  const float* hb = h + ((size_t)b*Nz + (Nz-64))*Dz;
  for (int i=t;i<16*Dz;i+=256){ int r=i>>8,c=i&255; wtL[r*257+c] = hb[(size_t)(m0+r)*Dz + c]; }
  __syncthreads();
  int r=t>>4, c0=t&15;
  float4 ak0=f4z(),ak1=f4z(),av0=f4z(),av1=f4z();
  for (int kk=0;kk<Dz;kk++){
    float hv = wtL[r*257+kk];
    const float4* wk4 = (const float4*)(Wwk + (size_t)kk*DCz);
    const float4* wv4 = (const float4*)(Wwv + (size_t)kk*DCz);
    fma4(ak0,hv,wk4[c0]); fma4(ak1,hv,wk4[c0+16]);
    fma4(av0,hv,wv4[c0]); fma4(av1,hv,wv4[c0+16]);
  }
  float4* ok = (float4*)(wkbuf + (size_t)(b*64 + m0+r)*DCz);
  float4* ov = (float4*)(wvbuf + (size_t)(b*64 + m0+r)*DCz);
  ok[c0]=ak0; ok[c0+16]=ak1; ov[c0]=av0; ov[c0+16]=av1;
}

__global__ __launch_bounds__(256) void k_cache_upd(float* __restrict__ cache,
    const float* __restrict__ wkbuf, const float* __restrict__ wvbuf,
    const float* __restrict__ Wwg, const float* __restrict__ bwg,
    int s0, int it, int pas){
  __shared__ float sqL[16*132];
  __shared__ float wkL[64*132];
  __shared__ float wat[16*68];
  __shared__ float ncL[16*132];
  __shared__ float wg[16];
  int t = threadIdx.x; int b = blockIdx.x;
  for (int i=t;i<16*DCz;i+=256){ int k2=i>>7,c=i&127; sqL[k2*132+c] = cache[((size_t)(b*NSLOTz)+s0+k2)*DSLOTz + c]; }
  for (int i=t;i<64*DCz;i+=256){ int m=i>>7,c=i&127; wkL[m*132+c] = wkbuf[(size_t)(b*64+m)*DCz+c]; }
  __syncthreads();
  {
    int k2 = t>>4;
    const float4* s4 = (const float4*)(sqL) + k2*33;
    for (int mm=0;mm<4;mm++){
      int m = (t&15) + 16*mm;
      const float4* k4 = (const float4*)(wkL) + m*33;
      float a=0.f;
      for (int d4=0;d4<32;d4++) a += dot4(s4[d4], k4[d4]);
      wat[k2*68+m] = a * 0.088388347648318447f;
    }
  }
  __syncthreads();
  if (t<16){
    float mx=-1e30f;
    for (int m=0;m<64;m++) mx = fmaxf(mx, wat[t*68+m]);
    float su=0.f;
    for (int m=0;m<64;m++){ float e=__expf(wat[t*68+m]-mx); wat[t*68+m]=e; su+=e; }
    float inv=1.f/su;
    for (int m=0;m<64;m++) wat[t*68+m]*=inv;
  }
  __syncthreads();
  {
    int k2=t>>4, c0=t&15;
    float4 a0=f4z(), a1=f4z();
    const float4* wvg = (const float4*)(wvbuf + (size_t)b*64*DCz);
    for (int m=0;m<64;m++){
      float a = wat[k2*68+m];
      fma4(a0,a,wvg[m*32+c0]); fma4(a1,a,wvg[m*32+c0+16]);
    }
    ((float4*)ncL)[k2*33+c0]=a0; ((float4*)ncL)[k2*33+16+c0]=a1;
  }
  __syncthreads();
  if (t<16){
    float a = bwg[0];
    for (int d2=0; d2<DCz; d2++) a += sqL[t*132+d2]*Wwg[d2] + ncL[t*132+d2]*Wwg[DCz+d2];
    wg[t] = sigm(a);
  }
  __syncthreads();
  for (int i=t;i<16*DCz;i+=256){
    int k2=i>>7,c=i&127;
    cache[((size_t)(b*NSLOTz)+s0+k2)*DSLOTz + c] = sqL[k2*132+c] + wg[k2]*ncL[k2*132+c];
  }
  if (t<16){
    float* cp = cache + ((size_t)(b*NSLOTz)+s0+t)*DSLOTz;
    cp[128] = wg[t];
    cp[137] = (it==0)?1.f:0.f; cp[138] = (it==1)?1.f:0.f; cp[139]=0.f; cp[140]=0.f;
    cp[141] = (pas==0)?1.f:0.f; cp[142] = (pas==1)?1.f:0.f; cp[143]=0.f; cp[144]=0.f;
  }
}

__global__ __launch_bounds__(256) void k_logits(const float* __restrict__ h,
    const float* __restrict__ Wout, const float* __restrict__ bout, float* __restrict__ out){
  __shared__ float hl[16*257];
  int t = threadIdx.x; int row0 = blockIdx.x*16;
  for (int i=t;i<16*Dz;i+=256){
    int rr=i>>8,c=i&255; int row=row0+rr; int b=row/Sz, s=row-b*Sz;
    hl[rr*257+c] = h[((size_t)b*Nz + TSz + s)*Dz + c];
  }
  __syncthreads();
  int rr = t>>4, v = t&15;
  float a = bout[v];
  for (int c=0;c<Dz;c++) a += hl[rr*257+c]*Wout[c*Vz + v];
  out[(size_t)(row0+rr)*Vz + v] = a;
}

__global__ __launch_bounds__(256) void k_feedback(float* __restrict__ h,
    const float* __restrict__ logits0, const float* __restrict__ pae,
    const float* __restrict__ Wfb, const float* __restrict__ bfb){
  __shared__ float trL[16*257];
  __shared__ float paeL[16*257];
  __shared__ int amL[16];
  int t = threadIdx.x; int b = blockIdx.y; int s0 = blockIdx.x*16;
  if (t<16){
    int s = s0+t; int am=0;
    if (s < Sz){
      const float* lg = logits0 + (size_t)(b*Sz+s)*Vz;
      float best = lg[0];
      for (int v=1;v<16;v++){ if (lg[v] > best){ best=lg[v]; am=v; } }
    }
    amL[t]=am;
  }
  for (int i=t;i<16*Dz;i+=256){
    int rr=i>>8,c=i&255; int s=s0+rr;
    trL[rr*257+c] = (s<Sz)? h[((size_t)b*Nz + TSz + s)*Dz + c] : 0.f;
  }
  __syncthreads();
  for (int i=t;i<16*Dz;i+=256){ int rr=i>>8,c=i&255; paeL[rr*257+c] = pae[(size_t)amL[rr]*Dz + c]; }
  __syncthreads();
  int r=t>>4, c0=t&15;
  float4 acc[4]; acc[0]=f4z(); acc[1]=f4z(); acc[2]=f4z(); acc[3]=f4z();
  for (int kk=0;kk<Dz;kk++){
    float xv = trL[r*257+kk];
    const float4* wr = (const float4*)(Wfb + (size_t)kk*Dz);
    fma4(acc[0],xv,wr[c0]); fma4(acc[1],xv,wr[c0+16]); fma4(acc[2],xv,wr[c0+32]); fma4(acc[3],xv,wr[c0+48]);
  }
  for (int kk=0;kk<Dz;kk++){
    float xv = paeL[r*257+kk];
    const float4* wr = (const float4*)(Wfb + (size_t)(Dz+kk)*Dz);
    fma4(acc[0],xv,wr[c0]); fma4(acc[1],xv,wr[c0+16]); fma4(acc[2],xv,wr[c0+32]); fma4(acc[3],xv,wr[c0+48]);
  }
  int s = s0+r;
  if (s < Sz){
    float* cp = h + ((size_t)b*Nz + TSz + s)*Dz;
    #pragma unroll
    for (int j=0;j<4;j++){
      float vals[4] = {acc[j].x, acc[j].y, acc[j].z, acc[j].w};
      #pragma unroll
      for (int q2=0;q2<4;q2++){
        int c = (c0+16*j)*4 + q2;
        float g = sigm(vals[q2] + bfb[c]);
        cp[c] = trL[r*257+c] + g*paeL[r*257+c];
      }
    }
  }
}

extern "C" void kernel_launch(void* const* d_in, const int* in_sizes, int n_in,
                              void* d_out, int out_size, void* d_ws, size_t ws_size,
                              hipStream_t stream){
  (void)in_sizes; (void)n_in;
  const int*   demo_in   = (const int*)d_in[0];
  const int*   demo_out  = (const int*)d_in[1];
  const int*   test_in   = (const int*)d_in[2];
  const float* token_emb = (const float*)d_in[3];
  const float* seg_emb   = (const float*)d_in[4];
  const float* slot_emb  = (const float*)d_in[5];
  const float* lid_emb   = (const float*)d_in[6];
  const float* Wq_read   = (const float*)d_in[7];
  const float* Wk_read   = (const float*)d_in[8];
  const float* Wv_read   = (const float*)d_in[9];
  const float* Wg_read   = (const float*)d_in[10];
  const float* bg_read   = (const float*)d_in[11];
  const float* Wqkv      = (const float*)d_in[12];
  const float* Wo        = (const float*)d_in[13];
  const float* Wwk       = (const float*)d_in[14];
  const float* Wwv       = (const float*)d_in[15];
  const float* Wwg       = (const float*)d_in[16];
  const float* bwg       = (const float*)d_in[17];
  const float* Wout      = (const float*)d_in[18];
  const float* bout      = (const float*)d_in[19];
  const float* pae       = (const float*)d_in[20];
  const float* Wfb       = (const float*)d_in[21];
  const float* bfb       = (const float*)d_in[22];

  char* wsb = (char*)d_ws;
  size_t off = 0;
  auto alloc = [&](size_t bytes)->char*{
    char* p = wsb + off;
    off += (bytes + 255) & ~(size_t)255;
    return p;
  };
  float* hbuf   = (float*)alloc((size_t)Bz*Nz*Dz*4);       // 103.2 MB
  float* kread  = (float*)alloc((size_t)Bz*NSLOTz*DCz*4);
  float* vread  = (float*)alloc((size_t)Bz*NSLOTz*Dz*4);
  float* cache  = (float*)alloc((size_t)Bz*NSLOTz*DSLOTz*4);
  float* kvbuf  = (float*)alloc((size_t)Bz*Hz*4160*4);
  float* wkbuf  = (float*)alloc((size_t)Bz*64*DCz*4);
  float* wvbuf  = (float*)alloc((size_t)Bz*64*DCz*4);
  float* logits0= (float*)alloc((size_t)Bz*Sz*Vz*4);
  float* cost   = (float*)alloc((size_t)Nz*32*4);
  float* sint   = (float*)alloc((size_t)Nz*32*4);

  if (off > ws_size){
    k_sentinel<<<(out_size+255)/256, 256, 0, stream>>>((float*)d_out, out_size);
    return;
  }

  k_rope<<<(Nz*32+255)/256, 256, 0, stream>>>(cost, sint);
  k_cache_init<<<(Bz*NSLOTz*DSLOTz+255)/256, 256, 0, stream>>>(slot_emb, lid_emb, cache);

  const int KVN = Bz*Hz*4160;
  for (int pas=0; pas<2; pas++){
    k_embed<<<(Bz*Nz*64+255)/256, 256, 0, stream>>>(demo_in, demo_out, test_in, token_emb, seg_emb, hbuf);
    if (pas==1)
      k_feedback<<<dim3(57,Bz), 256, 0, stream>>>(hbuf, logits0, pae, Wfb, bfb);
    for (int l=0; l<3; l++){
      for (int it=0; it<2; it++){
        k_proj_cache<<<Bz*NSLOTz, 384, 0, stream>>>(cache,
            Wk_read + (size_t)l*DSLOTz*DCz, Wv_read + (size_t)l*DSLOTz*Dz, kread, vread);
        k_read_attn<<<dim3(394,Bz), 256, 0, stream>>>(kread, vread,
            Wq_read + (size_t)l*Dz*DCz, Wg_read + (size_t)l*Dz, bg_read + l, hbuf);
        k_zero<<<(KVN+255)/256, 256, 0, stream>>>(kvbuf, KVN);
        k_kv<<<dim3(GXA,Bz), 256, 0, stream>>>(hbuf,
            Wqkv + (size_t)l*Dz*768, cost, sint, kvbuf);
        k_att<<<dim3(GXA,Bz), 256, 0, stream>>>(hbuf,
            Wqkv + (size_t)l*Dz*768, kvbuf, Wo + (size_t)l*Dz*Dz, cost, sint);
        k_wkv<<<dim3(4,Bz), 256, 0, stream>>>(hbuf,
            Wwk + (size_t)l*Dz*DCz, Wwv + (size_t)l*Dz*DCz, wkbuf, wvbuf);
        k_cache_upd<<<Bz, 256, 0, stream>>>(cache, wkbuf, wvbuf,
            Wwg + (size_t)l*2*DCz, bwg + l, l*16, it, pas);
      }
    }
    float* outp = (pas==0) ? logits0 : (float*)d_out;
    k_logits<<<900, 256, 0, stream>>>(hbuf, Wout, bout, outp);
  }
}

// Round 5
// 19159.392 us; speedup vs baseline: 2.6273x; 1.0722x over previous
//
#include <hip/hip_runtime.h>
#include <math.h>

#define Bz 16
#define Sz 900
#define Vz 16
#define Dz 256
#define DCz 128
#define Hz 4
#define Nz 6300
#define TSz 5400
#define DSLOTz 145
#define NSLOTz 48
#define GXA 99    // ceil(6300/64) row-blocks for k_kv/k_att
#define GXR 197   // ceil(6300/32) row-blocks for k_read_attn

typedef unsigned short u16;
typedef unsigned int u32;

static __device__ __forceinline__ float sigm(float x){ return 1.0f/(1.0f+__expf(-x)); }
static __device__ __forceinline__ void fma4(float4& a, float s, float4 b){ a.x+=s*b.x; a.y+=s*b.y; a.z+=s*b.z; a.w+=s*b.w; }
static __device__ __forceinline__ float dot4(float4 a, float4 b){ return a.x*b.x + a.y*b.y + a.z*b.z + a.w*b.w; }
static __device__ __forceinline__ float4 f4z(){ float4 z; z.x=0.f; z.y=0.f; z.z=0.f; z.w=0.f; return z; }
static __device__ __forceinline__ float elu1(float x){ return x>0.f ? x+1.f : __expf(x); }
static __device__ __forceinline__ float fcomp(float4 v, int i){ return (i==0)?v.x:(i==1)?v.y:(i==2)?v.z:v.w; }

__global__ void k_sentinel(float* out, int nelem){
  int i = blockIdx.x*256 + threadIdx.x;
  if (i < nelem) out[i] = 12345.0f;
}

__global__ void k_zero(float* p, int n){
  int i = blockIdx.x*256 + threadIdx.x;
  if (i < n) p[i] = 0.f;
}

__global__ void k_rope(float* cost, float* sint){
  int i = blockIdx.x*256 + threadIdx.x;
  if (i >= Nz*32) return;
  int n = i>>5, f = i&31;
  double invd = pow(10000.0, -(double)f/32.0);
  double fr = (double)n * invd;
  cost[i] = (float)cos(fr);
  sint[i] = (float)sin(fr);
}

__global__ void k_embed(const int* __restrict__ di, const int* __restrict__ dq,
                        const int* __restrict__ ti, const float* __restrict__ temb,
                        const float* __restrict__ semb, float* __restrict__ h){
  int i = blockIdx.x*256 + threadIdx.x;   // over B*N*64 float4s
  if (i >= Bz*Nz*64) return;
  int dv = i & 63; int bn = i >> 6; int n = bn % Nz; int b = bn / Nz;
  int tok;
  if (n < TSz){
    int nd = n/1800; int r = n - nd*1800;
    tok = (r < Sz) ? di[(b*3+nd)*Sz + r] : dq[(b*3+nd)*Sz + (r-Sz)];
  } else {
    tok = ti[b*Sz + (n-TSz)];
  }
  const float4* e4 = (const float4*)(temb + (size_t)tok*Dz);
  const float4* s4 = (const float4*)semb;
  float4 v = e4[dv]; float4 s = s4[dv];
  v.x += s.x; v.y += s.y; v.z += s.z; v.w += s.w;
  ((float4*)h)[(size_t)bn*64 + dv] = v;
}

__global__ void k_cache_init(const float* __restrict__ slot_emb, const float* __restrict__ lid,
                             float* __restrict__ cache){
  int i = blockIdx.x*256 + threadIdx.x;
  if (i >= Bz*NSLOTz*DSLOTz) return;
  int c = i % DSLOTz; int sc = (i / DSLOTz) % NSLOTz; int l = sc >> 4;
  float v = 0.f;
  if (c < DCz) v = slot_emb[sc*DCz + c];
  else if (c >= 129 && c < 137) v = lid[l*8 + (c-129)];
  cache[i] = v;
}

__global__ __launch_bounds__(384) void k_proj_cache(const float* __restrict__ cache,
    const float* __restrict__ Wk, const float* __restrict__ Wv,
    float* __restrict__ kread, float* __restrict__ vread){
  __shared__ float crow[DSLOTz];
  int b = blockIdx.x / NSLOTz, sc = blockIdx.x % NSLOTz;
  int t = threadIdx.x;
  const float* cp = cache + (size_t)(b*NSLOTz+sc)*DSLOTz;
  if (t < DSLOTz) crow[t] = cp[t];
  __syncthreads();
  if (t < DCz){
    float a = 0.f;
    for (int r2=0;r2<DSLOTz;r2++) a += crow[r2]*Wk[r2*DCz + t];
    kread[(size_t)(b*NSLOTz+sc)*DCz + t] = a;
  } else {
    int d = t - DCz;
    float a = 0.f;
    for (int r2=0;r2<DSLOTz;r2++) a += crow[r2]*Wv[r2*Dz + d];
    vread[(size_t)(b*NSLOTz+sc)*Dz + d] = a;
  }
}

// read-attention: 32-row tiles, LDS-staged Wq (K-tile 16), gate fused in GEMM.
// LDS: W [0,4096) wT/vT ; H [4096,4672) hT 16x36 ; G [4672,4688) wg ;
//      K [4688,11024) kL 48x132 ; Q [11024,15248) qL 32x132 ; A [15248,16816) attL 32x49
#define RA_W 0
#define RA_H 4096
#define RA_G 4672
#define RA_K 4688
#define RA_Q 11024
#define RA_A 15248
__global__ __launch_bounds__(256) void k_read_attn(
    const float* __restrict__ kread, const float* __restrict__ vread,
    const float* __restrict__ Wq, const float* __restrict__ Wg, const float* __restrict__ bg,
    float* __restrict__ h){
  __shared__ float smem[16816];
  const int t = threadIdx.x;
  const int b = blockIdx.y;
  const int n0 = blockIdx.x*32;
  const int c0 = t&15, rr = t>>4;
  float* hb = h + (size_t)b*Nz*Dz;
  for (int id=t; id<1536; id+=256){
    int s=id>>5, d4=id&31;
    ((float4*)(smem+RA_K))[s*33+d4] = ((const float4*)(kread + ((size_t)b*NSLOTz+s)*DCz))[d4];
  }
  float4 qa[2][2];
  qa[0][0]=f4z(); qa[0][1]=f4z(); qa[1][0]=f4z(); qa[1][1]=f4z();
  float gacc0=0.f, gacc1=0.f;
  for (int kt=0; kt<256; kt+=16){
    __syncthreads();
    for (int id=t; id<512; id+=256){
      int wr=id>>5, cf=id&31;
      ((float4*)(smem+RA_W))[wr*32+cf] = ((const float4*)(Wq + (size_t)(kt+wr)*DCz))[cf];
    }
    if (t<128){
      int row=t>>2, u=t&3;
      int n=n0+row;
      float4 hv = (n<Nz)? ((const float4*)(hb + (size_t)n*Dz))[(kt>>2)+u] : f4z();
      float* hp = smem + RA_H + row;
      hp[(4*u+0)*36]=hv.x; hp[(4*u+1)*36]=hv.y; hp[(4*u+2)*36]=hv.z; hp[(4*u+3)*36]=hv.w;
    }
    if (t<16) smem[RA_G+t] = Wg[kt+t];
    __syncthreads();
    for (int kk=0; kk<16; kk++){
      float2 h2 = *(const float2*)(smem + RA_H + kk*36 + 2*rr);
      const float4* wrow = (const float4*)(smem+RA_W) + kk*32;
      float4 w0=wrow[c0], w1=wrow[c0+16];
      float wg = smem[RA_G+kk];
      fma4(qa[0][0],h2.x,w0); fma4(qa[0][1],h2.x,w1);
      fma4(qa[1][0],h2.y,w0); fma4(qa[1][1],h2.y,w1);
      gacc0 += h2.x*wg; gacc1 += h2.y*wg;
    }
  }
  __syncthreads();
  ((float4*)(smem+RA_Q))[(2*rr+0)*33 + c0]      = qa[0][0];
  ((float4*)(smem+RA_Q))[(2*rr+0)*33 + 16 + c0] = qa[0][1];
  ((float4*)(smem+RA_Q))[(2*rr+1)*33 + c0]      = qa[1][0];
  ((float4*)(smem+RA_Q))[(2*rr+1)*33 + 16 + c0] = qa[1][1];
  __syncthreads();
  {
    int row = t&31, sg = t>>5;
    const float4* q4 = (const float4*)(smem+RA_Q) + row*33;
    for (int ss=0; ss<6; ss++){
      int s = sg*6+ss;
      const float4* k4 = (const float4*)(smem+RA_K) + s*33;
      float a=0.f;
      for (int d4=0; d4<32; d4++) a += dot4(q4[d4], k4[d4]);
      smem[RA_A + row*49 + s] = a*0.088388347648318447f;
    }
  }
  __syncthreads();
  if (t<32){
    float* ar = smem + RA_A + t*49;
    float mx=-1e30f;
    for (int s=0;s<48;s++) mx=fmaxf(mx,ar[s]);
    float su=0.f;
    for (int s=0;s<48;s++){ float e=__expf(ar[s]-mx); ar[s]=e; su+=e; }
    float inv=1.f/su;
    for (int s=0;s<48;s++) ar[s]*=inv;
  }
  float4 ov[2][4];
  #pragma unroll
  for (int i=0;i<2;i++){
    #pragma unroll
    for (int j=0;j<4;j++) ov[i][j]=f4z();
  }
  for (int sc=0; sc<3; sc++){
    __syncthreads();
    for (int id=t; id<1024; id+=256){
      int sr=id>>6, cf=id&63;
      ((float4*)(smem+RA_W))[sr*64+cf] = ((const float4*)(vread + ((size_t)b*NSLOTz + sc*16+sr)*Dz))[cf];
    }
    __syncthreads();
    for (int ss=0; ss<16; ss++){
      int s = sc*16+ss;
      float a0 = smem[RA_A + (2*rr+0)*49 + s];
      float a1 = smem[RA_A + (2*rr+1)*49 + s];
      const float4* vrow = (const float4*)(smem+RA_W) + ss*64;
      float4 v0=vrow[c0], v1=vrow[c0+16], v2=vrow[c0+32], v3=vrow[c0+48];
      fma4(ov[0][0],a0,v0); fma4(ov[0][1],a0,v1); fma4(ov[0][2],a0,v2); fma4(ov[0][3],a0,v3);
      fma4(ov[1][0],a1,v0); fma4(ov[1][1],a1,v1); fma4(ov[1][2],a1,v2); fma4(ov[1][3],a1,v3);
    }
  }
  float g0 = sigm(gacc0 + bg[0]);
  float g1 = sigm(gacc1 + bg[0]);
  #pragma unroll
  for (int i=0;i<2;i++){
    int n = n0 + 2*rr + i;
    if (n < Nz){
      float g = i ? g1 : g0;
      float4* hp = (float4*)(hb + (size_t)n*Dz);
      #pragma unroll
      for (int j=0;j<4;j++){
        float4 hv = hp[c0+16*j];
        float4 o = ov[i][j];
        hv.x += g*o.x; hv.y += g*o.y; hv.z += g*o.z; hv.w += g*o.w;
        hp[c0+16*j] = hv;
      }
    }
  }
}

// k/v projection (Wqkv cols 256..768) + rope/elu + fused kv accumulation.
// 64-row tiles, K-tile 16. LDS: wT [0,8192) 16x512 ; hT [8192,9280) 16x68 ; P2 reuses [0,8704).
__global__ __launch_bounds__(256) void k_kv(const float* __restrict__ h,
    const float* __restrict__ Wl, const float* __restrict__ cost, const float* __restrict__ sint,
    float* __restrict__ kvbuf){
  __shared__ float smem[9280];
  const int t = threadIdx.x;
  const int b = blockIdx.y;
  const int n0 = blockIdx.x*64;
  const int c0 = t&15, rr = t>>4;
  const float* hb = h + (size_t)b*Nz*Dz;
  float4 ka[4][4], va[4][4];
  #pragma unroll
  for (int i=0;i<4;i++){
    #pragma unroll
    for (int j=0;j<4;j++){ ka[i][j]=f4z(); va[i][j]=f4z(); }
  }
  for (int kt=0; kt<256; kt+=16){
    __syncthreads();
    for (int id=t; id<2048; id+=256){
      int wr = id>>7, cf = id&127;
      ((float4*)smem)[wr*128+cf] = ((const float4*)(Wl + (size_t)(kt+wr)*768 + 256))[cf];
    }
    {
      int row = t>>2, u = t&3;
      int n = n0 + row;
      float4 hv = (n<Nz) ? ((const float4*)(hb + (size_t)n*Dz))[(kt>>2)+u] : f4z();
      float* hp = smem + 8192 + row;
      hp[(4*u+0)*68]=hv.x; hp[(4*u+1)*68]=hv.y; hp[(4*u+2)*68]=hv.z; hp[(4*u+3)*68]=hv.w;
    }
    __syncthreads();
    for (int kk=0; kk<16; kk++){
      float4 hv = *(const float4*)(smem + 8192 + kk*68 + 4*rr);
      const float4* wrow = (const float4*)smem + kk*128;
      float4 wk0=wrow[c0], wk1=wrow[c0+16], wk2=wrow[c0+32], wk3=wrow[c0+48];
      float4 wv0=wrow[64+c0], wv1=wrow[64+c0+16], wv2=wrow[64+c0+32], wv3=wrow[64+c0+48];
      #pragma unroll
      for (int i=0;i<4;i++){
        float hc = fcomp(hv, i);
        fma4(ka[i][0],hc,wk0); fma4(ka[i][1],hc,wk1); fma4(ka[i][2],hc,wk2); fma4(ka[i][3],hc,wk3);
        fma4(va[i][0],hc,wv0); fma4(va[i][1],hc,wv1); fma4(va[i][2],hc,wv2); fma4(va[i][3],hc,wv3);
      }
    }
  }
  #pragma unroll
  for (int i=0;i<4;i++){
    int n = n0 + 4*rr + i;
    int valid = (n < Nz);
    int nc = valid ? n : 0;
    float co0 = cost[nc*32 + 2*c0], si0 = sint[nc*32 + 2*c0];
    float co1 = cost[nc*32 + 2*c0+1], si1 = sint[nc*32 + 2*c0+1];
    #pragma unroll
    for (int j=0;j<4;j++){
      float4 kin = ka[i][j];
      float r0 = kin.x*co0 - kin.y*si0;
      float r1 = kin.x*si0 + kin.y*co0;
      float r2 = kin.z*co1 - kin.w*si1;
      float r3 = kin.z*si1 + kin.w*co1;
      float4 ko;
      ko.x = valid ? elu1(r0) : 0.f;
      ko.y = valid ? elu1(r1) : 0.f;
      ko.z = valid ? elu1(r2) : 0.f;
      ko.w = valid ? elu1(r3) : 0.f;
      ka[i][j] = ko;
    }
  }
  const int d = t&63, q4 = t>>6;
  float* kvb = kvbuf + (size_t)(b*Hz)*4160;
  #pragma unroll
  for (int g=0; g<4; g++){
    __syncthreads();
    #pragma unroll
    for (int i=0;i<4;i++){
      *(float4*)(smem + (4*rr+i)*68 + 4*c0)        = ka[i][g];
      *(float4*)(smem + 4352 + (4*rr+i)*68 + 4*c0) = va[i][g];
    }
    __syncthreads();
    float4 kvacc[4];
    #pragma unroll
    for (int u=0;u<4;u++) kvacc[u]=f4z();
    float ksl = 0.f;
    for (int row=0; row<64; row++){
      float kd = smem[row*68 + d];
      ksl += kd;
      const float4* vp = (const float4*)(smem + 4352 + row*68);
      #pragma unroll
      for (int u=0;u<4;u++) fma4(kvacc[u], kd, vp[q4*4+u]);
    }
    float* kq = kvb + g*4160;
    #pragma unroll
    for (int u=0;u<4;u++){
      int e = q4*16 + 4*u;
      atomicAdd(&kq[(e+0)*64+d], kvacc[u].x);
      atomicAdd(&kq[(e+1)*64+d], kvacc[u].y);
      atomicAdd(&kq[(e+2)*64+d], kvacc[u].z);
      atomicAdd(&kq[(e+3)*64+d], kvacc[u].w);
    }
    if (q4==0) atomicAdd(&kq[4096+d], ksl);
  }
}

// P[b][h] = kv_h @ Wo_h  (64 x 256, K=64). grid: Bz*Hz blocks.
__global__ __launch_bounds__(256) void k_pmat(const float* __restrict__ kvbuf,
    const float* __restrict__ Wo, float* __restrict__ pmat){
  __shared__ float smem[8448]; // kvL [0,4352) 64x68 ; wT [4352,8448) 16x256
  const int t = threadIdx.x;
  const int bh = blockIdx.x;
  const int hh = bh & 3;
  const int c0 = t&15, rr = t>>4;
  const float* kvp = kvbuf + (size_t)bh*4160;
  for (int id=t; id<4096; id+=256){
    int e=id>>6, d=id&63;
    smem[e*68+d] = kvp[id];
  }
  float4 acc[4][4];
  #pragma unroll
  for (int i=0;i<4;i++){
    #pragma unroll
    for (int j=0;j<4;j++) acc[i][j]=f4z();
  }
  for (int kt=0; kt<64; kt+=16){
    __syncthreads();
    for (int id=t; id<1024; id+=256){
      int wr=id>>6, cf=id&63;
      ((float4*)(smem+4352))[wr*64+cf] = ((const float4*)(Wo + (size_t)(hh*64+kt+wr)*256))[cf];
    }
    __syncthreads();
    for (int kk=0; kk<16; kk++){
      float4 a4 = *(const float4*)(smem + (kt+kk)*68 + 4*rr);
      const float4* wrow = (const float4*)(smem+4352) + kk*64;
      float4 w0=wrow[c0], w1=wrow[c0+16], w2=wrow[c0+32], w3=wrow[c0+48];
      #pragma unroll
      for (int i=0;i<4;i++){
        float ac = fcomp(a4,i);
        fma4(acc[i][0],ac,w0); fma4(acc[i][1],ac,w1); fma4(acc[i][2],ac,w2); fma4(acc[i][3],ac,w3);
      }
    }
  }
  float* Pp = pmat + (size_t)bh*16384;
  #pragma unroll
  for (int i=0;i<4;i++){
    #pragma unroll
    for (int j=0;j<4;j++) ((float4*)Pp)[(4*rr+i)*64 + c0 + 16*j] = acc[i][j];
  }
}

// q projection + rope/elu + z (shuffle) + qz@P GEMM + residual.
// LDS: W [0,4096) ; hT [4096,5184) 16x68 ; qzT [5184,9536) 64x68 ; ksum [9536,9792)
__global__ __launch_bounds__(256) void k_att(
    float* __restrict__ h, const float* __restrict__ Wq768,
    const float* __restrict__ kvbuf, const float* __restrict__ pmat,
    const float* __restrict__ cost, const float* __restrict__ sint){
  __shared__ float smem[9792];
  const int t = threadIdx.x;
  const int b = blockIdx.y;
  const int n0 = blockIdx.x*64;
  const int c0 = t&15, rr = t>>4;
  float* hb = h + (size_t)b*Nz*Dz;
  {
    int head = t>>6, hd = t&63;
    smem[9536 + t] = kvbuf[(size_t)(b*Hz+head)*4160 + 4096 + hd];
  }
  float4 qa[4][4];
  #pragma unroll
  for (int i=0;i<4;i++){
    #pragma unroll
    for (int j=0;j<4;j++) qa[i][j]=f4z();
  }
  for (int kt=0; kt<256; kt+=16){
    __syncthreads();
    for (int id=t; id<1024; id+=256){
      int wr=id>>6, cf=id&63;
      ((float4*)smem)[wr*64+cf] = ((const float4*)(Wq768 + (size_t)(kt+wr)*768))[cf];
    }
    {
      int row=t>>2, u=t&3;
      int n = n0+row;
      float4 hv = (n<Nz)? ((const float4*)(hb + (size_t)n*Dz))[(kt>>2)+u] : f4z();
      float* hp = smem + 4096 + row;
      hp[(4*u+0)*68]=hv.x; hp[(4*u+1)*68]=hv.y; hp[(4*u+2)*68]=hv.z; hp[(4*u+3)*68]=hv.w;
    }
    __syncthreads();
    for (int kk=0; kk<16; kk++){
      float4 hv = *(const float4*)(smem + 4096 + kk*68 + 4*rr);
      const float4* wrow = (const float4*)smem + kk*64;
      float4 w0=wrow[c0], w1=wrow[c0+16], w2=wrow[c0+32], w3=wrow[c0+48];
      #pragma unroll
      for (int i=0;i<4;i++){
        float hc = fcomp(hv, i);
        fma4(qa[i][0],hc,w0); fma4(qa[i][1],hc,w1); fma4(qa[i][2],hc,w2); fma4(qa[i][3],hc,w3);
      }
    }
  }
  // rope + elu (head=j, hd=4c0+q)
  #pragma unroll
  for (int i=0;i<4;i++){
    int n = n0 + 4*rr + i;
    int nc = (n < Nz) ? n : 0;
    float co0 = cost[nc*32 + 2*c0], si0 = sint[nc*32 + 2*c0];
    float co1 = cost[nc*32 + 2*c0+1], si1 = sint[nc*32 + 2*c0+1];
    #pragma unroll
    for (int j=0;j<4;j++){
      float4 qi = qa[i][j];
      float4 qo;
      qo.x = elu1(qi.x*co0 - qi.y*si0);
      qo.y = elu1(qi.x*si0 + qi.y*co0);
      qo.z = elu1(qi.z*co1 - qi.w*si1);
      qo.w = elu1(qi.z*si1 + qi.w*co1);
      qa[i][j] = qo;
    }
  }
  // z = 1/(qf . ksum + 1e-6) per (row,head), butterfly over the 16 c0-lanes; fold into qa
  {
    float p[4][4];
    #pragma unroll
    for (int i=0;i<4;i++)
      #pragma unroll
      for (int j=0;j<4;j++)
        p[i][j] = dot4(qa[i][j], *(const float4*)(smem + 9536 + j*64 + 4*c0));
    #pragma unroll
    for (int m=1; m<16; m<<=1){
      #pragma unroll
      for (int i=0;i<4;i++)
        #pragma unroll
        for (int j=0;j<4;j++)
          p[i][j] += __shfl_xor(p[i][j], m, 64);
    }
    #pragma unroll
    for (int i=0;i<4;i++)
      #pragma unroll
      for (int j=0;j<4;j++){
        float zv = 1.f/(p[i][j] + 1e-6f);
        qa[i][j].x *= zv; qa[i][j].y *= zv; qa[i][j].z *= zv; qa[i][j].w *= zv;
      }
  }
  float4 oa[4][4];
  #pragma unroll
  for (int i=0;i<4;i++){
    #pragma unroll
    for (int j=0;j<4;j++) oa[i][j]=f4z();
  }
  #pragma unroll
  for (int hh=0; hh<4; hh++){
    __syncthreads();
    #pragma unroll
    for (int i=0;i<4;i++){
      float4 qv = qa[i][hh];
      int R = 4*rr+i;
      float* qz = smem + 5184;
      qz[(4*c0+0)*68 + R] = qv.x;
      qz[(4*c0+1)*68 + R] = qv.y;
      qz[(4*c0+2)*68 + R] = qv.z;
      qz[(4*c0+3)*68 + R] = qv.w;
    }
    __syncthreads();
    const float* Ph = pmat + (size_t)(b*Hz+hh)*16384;
    for (int kt2=0; kt2<64; kt2+=16){
      for (int id=t; id<1024; id+=256){
        int wr=id>>6, cf=id&63;
        ((float4*)smem)[wr*64+cf] = ((const float4*)(Ph + (size_t)(kt2+wr)*256))[cf];
      }
      __syncthreads();
      for (int kk=0; kk<16; kk++){
        float4 av = *(const float4*)(smem + 5184 + (kt2+kk)*68 + 4*rr);
        const float4* wrow = (const float4*)smem + kk*64;
        float4 w0=wrow[c0], w1=wrow[c0+16], w2=wrow[c0+32], w3=wrow[c0+48];
        #pragma unroll
        for (int i=0;i<4;i++){
          float ac = fcomp(av, i);
          fma4(oa[i][0],ac,w0); fma4(oa[i][1],ac,w1); fma4(oa[i][2],ac,w2); fma4(oa[i][3],ac,w3);
        }
      }
      __syncthreads();
    }
  }
  #pragma unroll
  for (int i=0;i<4;i++){
    int n = n0 + 4*rr + i;
    if (n < Nz){
      float4* hp = (float4*)(hb + (size_t)n*Dz);
      #pragma unroll
      for (int j=0;j<4;j++){
        float4 hv = hp[c0+16*j];
        hv.x += oa[i][j].x; hv.y += oa[i][j].y; hv.z += oa[i][j].z; hv.w += oa[i][j].w;
        hp[c0+16*j] = hv;
      }
    }
  }
}

__global__ __launch_bounds__(256) void k_wkv(const float* __restrict__ h,
    const float* __restrict__ Wwk, const float* __restrict__ Wwv,
    float* __restrict__ wkbuf, float* __restrict__ wvbuf){
  __shared__ float wtL[16*257];
  int t = threadIdx.x;
  int b = blockIdx.y, m0 = blockIdx.x*16;
  const float* hb = h + ((size_t)b*Nz + (Nz-64))*Dz;
  for (int i=t;i<16*Dz;i+=256){ int r=i>>8,c=i&255; wtL[r*257+c] = hb[(size_t)(m0+r)*Dz + c]; }
  __syncthreads();
  int r=t>>4, c0=t&15;
  float4 ak0=f4z(),ak1=f4z(),av0=f4z(),av1=f4z();
  for (int kk=0;kk<Dz;kk++){
    float hv = wtL[r*257+kk];
    const float4* wk4 = (const float4*)(Wwk + (size_t)kk*DCz);
    const float4* wv4 = (const float4*)(Wwv + (size_t)kk*DCz);
    fma4(ak0,hv,wk4[c0]); fma4(ak1,hv,wk4[c0+16]);
    fma4(av0,hv,wv4[c0]); fma4(av1,hv,wv4[c0+16]);
  }
  float4* ok = (float4*)(wkbuf + (size_t)(b*64 + m0+r)*DCz);
  float4* ov = (float4*)(wvbuf + (size_t)(b*64 + m0+r)*DCz);
  ok[c0]=ak0; ok[c0+16]=ak1; ov[c0]=av0; ov[c0+16]=av1;
}

__global__ __launch_bounds__(256) void k_cache_upd(float* __restrict__ cache,
    const float* __restrict__ wkbuf, const float* __restrict__ wvbuf,
    const float* __restrict__ Wwg, const float* __restrict__ bwg,
    int s0, int it, int pas){
  __shared__ float sqL[16*132];
  __shared__ float wkL[64*132];
  __shared__ float wat[16*68];
  __shared__ float ncL[16*132];
  __shared__ float wg[16];
  int t = threadIdx.x; int b = blockIdx.x;
  for (int i=t;i<16*DCz;i+=256){ int k2=i>>7,c=i&127; sqL[k2*132+c] = cache[((size_t)(b*NSLOTz)+s0+k2)*DSLOTz + c]; }
  for (int i=t;i<64*DCz;i+=256){ int m=i>>7,c=i&127; wkL[m*132+c] = wkbuf[(size_t)(b*64+m)*DCz+c]; }
  __syncthreads();
  {
    int k2 = t>>4;
    const float4* s4 = (const float4*)(sqL) + k2*33;
    for (int mm=0;mm<4;mm++){
      int m = (t&15) + 16*mm;
      const float4* k4 = (const float4*)(wkL) + m*33;
      float a=0.f;
      for (int d4=0;d4<32;d4++) a += dot4(s4[d4], k4[d4]);
      wat[k2*68+m] = a * 0.088388347648318447f;
    }
  }
  __syncthreads();
  if (t<16){
    float mx=-1e30f;
    for (int m=0;m<64;m++) mx = fmaxf(mx, wat[t*68+m]);
    float su=0.f;
    for (int m=0;m<64;m++){ float e=__expf(wat[t*68+m]-mx); wat[t*68+m]=e; su+=e; }
    float inv=1.f/su;
    for (int m=0;m<64;m++) wat[t*68+m]*=inv;
  }
  __syncthreads();
  {
    int k2=t>>4, c0=t&15;
    float4 a0=f4z(), a1=f4z();
    const float4* wvg = (const float4*)(wvbuf + (size_t)b*64*DCz);
    for (int m=0;m<64;m++){
      float a = wat[k2*68+m];
      fma4(a0,a,wvg[m*32+c0]); fma4(a1,a,wvg[m*32+c0+16]);
    }
    ((float4*)ncL)[k2*33+c0]=a0; ((float4*)ncL)[k2*33+16+c0]=a1;
  }
  __syncthreads();
  if (t<16){
    float a = bwg[0];
    for (int d2=0; d2<DCz; d2++) a += sqL[t*132+d2]*Wwg[d2] + ncL[t*132+d2]*Wwg[DCz+d2];
    wg[t] = sigm(a);
  }
  __syncthreads();
  for (int i=t;i<16*DCz;i+=256){
    int k2=i>>7,c=i&127;
    cache[((size_t)(b*NSLOTz)+s0+k2)*DSLOTz + c] = sqL[k2*132+c] + wg[k2]*ncL[k2*132+c];
  }
  if (t<16){
    float* cp = cache + ((size_t)(b*NSLOTz)+s0+t)*DSLOTz;
    cp[128] = wg[t];
    cp[137] = (it==0)?1.f:0.f; cp[138] = (it==1)?1.f:0.f; cp[139]=0.f; cp[140]=0.f;
    cp[141] = (pas==0)?1.f:0.f; cp[142] = (pas==1)?1.f:0.f; cp[143]=0.f; cp[144]=0.f;
  }
}

__global__ __launch_bounds__(256) void k_logits(const float* __restrict__ h,
    const float* __restrict__ Wout, const float* __restrict__ bout, float* __restrict__ out){
  __shared__ float hl[16*257];
  int t = threadIdx.x; int row0 = blockIdx.x*16;
  for (int i=t;i<16*Dz;i+=256){
    int rr=i>>8,c=i&255; int row=row0+rr; int b=row/Sz, s=row-b*Sz;
    hl[rr*257+c] = h[((size_t)b*Nz + TSz + s)*Dz + c];
  }
  __syncthreads();
  int rr = t>>4, v = t&15;
  float a = bout[v];
  for (int c=0;c<Dz;c++) a += hl[rr*257+c]*Wout[c*Vz + v];
  out[(size_t)(row0+rr)*Vz + v] = a;
}

__global__ __launch_bounds__(256) void k_feedback(float* __restrict__ h,
    const float* __restrict__ logits0, const float* __restrict__ pae,
    const float* __restrict__ Wfb, const float* __restrict__ bfb){
  __shared__ float trL[16*257];
  __shared__ float paeL[16*257];
  __shared__ int amL[16];
  int t = threadIdx.x; int b = blockIdx.y; int s0 = blockIdx.x*16;
  if (t<16){
    int s = s0+t; int am=0;
    if (s < Sz){
      const float* lg = logits0 + (size_t)(b*Sz+s)*Vz;
      float best = lg[0];
      for (int v=1;v<16;v++){ if (lg[v] > best){ best=lg[v]; am=v; } }
    }
    amL[t]=am;
  }
  for (int i=t;i<16*Dz;i+=256){
    int rr=i>>8,c=i&255; int s=s0+rr;
    trL[rr*257+c] = (s<Sz)? h[((size_t)b*Nz + TSz + s)*Dz + c] : 0.f;
  }
  __syncthreads();
  for (int i=t;i<16*Dz;i+=256){ int rr=i>>8,c=i&255; paeL[rr*257+c] = pae[(size_t)amL[rr]*Dz + c]; }
  __syncthreads();
  int r=t>>4, c0=t&15;
  float4 acc[4]; acc[0]=f4z(); acc[1]=f4z(); acc[2]=f4z(); acc[3]=f4z();
  for (int kk=0;kk<Dz;kk++){
    float xv = trL[r*257+kk];
    const float4* wr = (const float4*)(Wfb + (size_t)kk*Dz);
    fma4(acc[0],xv,wr[c0]); fma4(acc[1],xv,wr[c0+16]); fma4(acc[2],xv,wr[c0+32]); fma4(acc[3],xv,wr[c0+48]);
  }
  for (int kk=0;kk<Dz;kk++){
    float xv = paeL[r*257+kk];
    const float4* wr = (const float4*)(Wfb + (size_t)(Dz+kk)*Dz);
    fma4(acc[0],xv,wr[c0]); fma4(acc[1],xv,wr[c0+16]); fma4(acc[2],xv,wr[c0+32]); fma4(acc[3],xv,wr[c0+48]);
  }
  int s = s0+r;
  if (s < Sz){
    float* cp = h + ((size_t)b*Nz + TSz + s)*Dz;
    #pragma unroll
    for (int j=0;j<4;j++){
      float vals[4] = {acc[j].x, acc[j].y, acc[j].z, acc[j].w};
      #pragma unroll
      for (int q2=0;q2<4;q2++){
        int c = (c0+16*j)*4 + q2;
        float g = sigm(vals[q2] + bfb[c]);
        cp[c] = trL[r*257+c] + g*paeL[r*257+c];
      }
    }
  }
}

extern "C" void kernel_launch(void* const* d_in, const int* in_sizes, int n_in,
                              void* d_out, int out_size, void* d_ws, size_t ws_size,
                              hipStream_t stream){
  (void)in_sizes; (void)n_in;
  const int*   demo_in   = (const int*)d_in[0];
  const int*   demo_out  = (const int*)d_in[1];
  const int*   test_in   = (const int*)d_in[2];
  const float* token_emb = (const float*)d_in[3];
  const float* seg_emb   = (const float*)d_in[4];
  const float* slot_emb  = (const float*)d_in[5];
  const float* lid_emb   = (const float*)d_in[6];
  const float* Wq_read   = (const float*)d_in[7];
  const float* Wk_read   = (const float*)d_in[8];
  const float* Wv_read   = (const float*)d_in[9];
  const float* Wg_read   = (const float*)d_in[10];
  const float* bg_read   = (const float*)d_in[11];
  const float* Wqkv      = (const float*)d_in[12];
  const float* Wo        = (const float*)d_in[13];
  const float* Wwk       = (const float*)d_in[14];
  const float* Wwv       = (const float*)d_in[15];
  const float* Wwg       = (const float*)d_in[16];
  const float* bwg       = (const float*)d_in[17];
  const float* Wout      = (const float*)d_in[18];
  const float* bout      = (const float*)d_in[19];
  const float* pae       = (const float*)d_in[20];
  const float* Wfb       = (const float*)d_in[21];
  const float* bfb       = (const float*)d_in[22];

  char* wsb = (char*)d_ws;
  size_t off = 0;
  auto alloc = [&](size_t bytes)->char*{
    char* p = wsb + off;
    off += (bytes + 255) & ~(size_t)255;
    return p;
  };
  float* hbuf   = (float*)alloc((size_t)Bz*Nz*Dz*4);
  float* kread  = (float*)alloc((size_t)Bz*NSLOTz*DCz*4);
  float* vread  = (float*)alloc((size_t)Bz*NSLOTz*Dz*4);
  float* cache  = (float*)alloc((size_t)Bz*NSLOTz*DSLOTz*4);
  float* kvbuf  = (float*)alloc((size_t)Bz*Hz*4160*4);
  float* pmat   = (float*)alloc((size_t)Bz*Hz*64*256*4);
  float* wkbuf  = (float*)alloc((size_t)Bz*64*DCz*4);
  float* wvbuf  = (float*)alloc((size_t)Bz*64*DCz*4);
  float* logits0= (float*)alloc((size_t)Bz*Sz*Vz*4);
  float* cost   = (float*)alloc((size_t)Nz*32*4);
  float* sint   = (float*)alloc((size_t)Nz*32*4);

  if (off > ws_size){
    k_sentinel<<<(out_size+255)/256, 256, 0, stream>>>((float*)d_out, out_size);
    return;
  }

  k_rope<<<(Nz*32+255)/256, 256, 0, stream>>>(cost, sint);
  k_cache_init<<<(Bz*NSLOTz*DSLOTz+255)/256, 256, 0, stream>>>(slot_emb, lid_emb, cache);

  const int KVN = Bz*Hz*4160;
  for (int pas=0; pas<2; pas++){
    k_embed<<<(Bz*Nz*64+255)/256, 256, 0, stream>>>(demo_in, demo_out, test_in, token_emb, seg_emb, hbuf);
    if (pas==1)
      k_feedback<<<dim3(57,Bz), 256, 0, stream>>>(hbuf, logits0, pae, Wfb, bfb);
    for (int l=0; l<3; l++){
      for (int it=0; it<2; it++){
        k_proj_cache<<<Bz*NSLOTz, 384, 0, stream>>>(cache,
            Wk_read + (size_t)l*DSLOTz*DCz, Wv_read + (size_t)l*DSLOTz*Dz, kread, vread);
        k_read_attn<<<dim3(GXR,Bz), 256, 0, stream>>>(kread, vread,
            Wq_read + (size_t)l*Dz*DCz, Wg_read + (size_t)l*Dz, bg_read + l, hbuf);
        k_zero<<<(KVN+255)/256, 256, 0, stream>>>(kvbuf, KVN);
        k_kv<<<dim3(GXA,Bz), 256, 0, stream>>>(hbuf,
            Wqkv + (size_t)l*Dz*768, cost, sint, kvbuf);
        k_pmat<<<Bz*Hz, 256, 0, stream>>>(kvbuf, Wo + (size_t)l*Dz*Dz, pmat);
        k_att<<<dim3(GXA,Bz), 256, 0, stream>>>(hbuf,
            Wqkv + (size_t)l*Dz*768, kvbuf, pmat, cost, sint);
        k_wkv<<<dim3(4,Bz), 256, 0, stream>>>(hbuf,
            Wwk + (size_t)l*Dz*DCz, Wwv + (size_t)l*Dz*DCz, wkbuf, wvbuf);
        k_cache_upd<<<Bz, 256, 0, stream>>>(cache, wkbuf, wvbuf,
            Wwg + (size_t)l*2*DCz, bwg + l, l*16, it, pas);
      }
    }
    float* outp = (pas==0) ? logits0 : (float*)d_out;
    k_logits<<<900, 256, 0, stream>>>(hbuf, Wout, bout, outp);
  }
}